// Round 11
// baseline (684.596 us; speedup 1.0000x reference)
//
#include <hip/hip_runtime.h>
#include <hip/hip_bf16.h>
#include <math.h>

#define NN 20000
#define NE 256000
#define NODE_DIM_ 128
#define EDGE_DIM_ 8
#define HID 64
#define HEADS 4
#define NLAYERS 3
#define NCLASSES 3
#define NGRAPHS 64
#define HC 256  // HEADS*HID
#define EB 64   // edges per block in edge_mlp
#define EPB 16  // nodes per block in epilogue

typedef __hip_bfloat16 bf16;
using v8s = __attribute__((ext_vector_type(8))) short;
using u16x8 = __attribute__((ext_vector_type(8))) unsigned short;
using f32x4 = __attribute__((ext_vector_type(4))) float;

__device__ __forceinline__ float B2F(bf16 x) { return __bfloat162float(x); }
__device__ __forceinline__ bf16 F2B(float x) { return __float2bfloat16(x); }
__device__ __forceinline__ short F2BS(float x) {
    union { bf16 b; short s; } u; u.b = __float2bfloat16(x); return u.s;
}
__device__ __forceinline__ float U2F(unsigned short u) { return __uint_as_float(((unsigned)u) << 16); }
__device__ __forceinline__ int clampi(int x, int lo, int hi) { return min(max(x, lo), hi); }

// ---------------- diagnostics ----------------
__global__ void gt_write_const(float* out, int n, float val) {
    int i = blockIdx.x * blockDim.x + threadIdx.x;
    if (i < n) out[i] = val;
}

// ---------------- utility ----------------
__global__ void gt_zero_i32(int* p, int n) {
    int i = blockIdx.x * blockDim.x + threadIdx.x;
    if (i < n) p[i] = 0;
}

// ---------------- degree-sorted node permutation (counting sort, descending) ----------
// Collapses intra-block degree variance in attn (block waits on its max-degree wave).
__global__ void gt_deg_hist(const int* __restrict__ cnt, int* __restrict__ bins) {
    int n = blockIdx.x * 256 + threadIdx.x;
    if (n < NN) atomicAdd(&bins[min(cnt[n], 255)], 1);
}

__global__ void gt_deg_scan(const int* __restrict__ bins, int* __restrict__ boff) {
    int d = threadIdx.x;   // 256 threads; descending order: offset = count of nodes with larger degree
    int s = 0;
    for (int j = d + 1; j < 256; ++j) s += bins[j];
    boff[d] = s;
}

__global__ void gt_deg_scatter(const int* __restrict__ cnt, int* __restrict__ boff,
                               int* __restrict__ perm) {
    int n = blockIdx.x * 256 + threadIdx.x;
    if (n < NN) {
        int d = min(cnt[n], 255);
        int p = atomicAdd(&boff[d], 1);
        if (p >= 0 && p < NN) perm[p] = n;
    }
}

// ---------------- Wqe = Wq-head @ We-head (fused qe weight) + bias4 ----------------
__global__ void gt_prep_wqe(const float* __restrict__ Wq, const float* __restrict__ bq,
                            const float* __restrict__ bk, const float* __restrict__ bv,
                            const float* __restrict__ We,
                            float* __restrict__ Wqe, float* __restrict__ bias4) {
    int b = blockIdx.x;
    int l = b / 65, kk = b % 65;
    int t = threadIdx.x;
    int hh = t >> 6, d = t & 63;
    const float* Weh = We + (size_t)l * HID * HC + (size_t)d * HC + hh * 64;
    if (kk < 64) {
        const float* Wqr = Wq + (size_t)l * HID * HC + (size_t)kk * HC + hh * 64;
        float s = 0.f;
        for (int c = 0; c < 64; ++c) s += Wqr[c] * Weh[c];
        Wqe[(size_t)l * HID * HC + (size_t)kk * HC + t] = s;
    } else {
        const float* bqr = bq + (size_t)l * HC + hh * 64;
        float s = 0.f;
        for (int c = 0; c < 64; ++c) s += bqr[c] * Weh[c];
        bias4[(size_t)l * 1024 + 768 + t] = s;
        bias4[(size_t)l * 1024 + t]       = bq[(size_t)l * HC + t];
        bias4[(size_t)l * 1024 + 256 + t] = bk[(size_t)l * HC + t];
        bias4[(size_t)l * 1024 + 512 + t] = bv[(size_t)l * HC + t];
    }
}

// ---------------- pack W4 = [Wq|Wk|Wv|Wqe] (64 x 1024) into per-fragment bf16 layout ----
__global__ void gt_pack_qkv(const float* __restrict__ Wq, const float* __restrict__ Wk,
                            const float* __restrict__ Wv, const float* __restrict__ Wqe,
                            bf16* __restrict__ Bp) {
    int idx = blockIdx.x * 256 + threadIdx.x;
    if (idx >= NLAYERS * 8192) return;
    int lane = idx & 63;
    int ks = (idx >> 6) & 1;
    int nf = (idx >> 7) & 63;
    int l = idx >> 13;
    int col = nf * 16 + (lane & 15);
    int k0 = ks * 32 + (lane >> 4) * 8;
    const float* src;
    int c;
    if (col < 256)      { src = Wq  + (size_t)l * HID * HC; c = col; }
    else if (col < 512) { src = Wk  + (size_t)l * HID * HC; c = col - 256; }
    else if (col < 768) { src = Wv  + (size_t)l * HID * HC; c = col - 512; }
    else                { src = Wqe + (size_t)l * HID * HC; c = col - 768; }
    bf16* dst = Bp + (size_t)idx * 8;
#pragma unroll
    for (int j = 0; j < 8; ++j) dst[j] = F2B(src[(size_t)(k0 + j) * HC + c]);
}

// ---------------- pack W2 (64x64) into fragment layout ----------------
__global__ void gt_pack_w2(const float* __restrict__ W2, bf16* __restrict__ B2p) {
    int idx = blockIdx.x * 256 + threadIdx.x;
    if (idx >= 512) return;
    int lane = idx & 63;
    int ks = (idx >> 6) & 1;
    int nf = idx >> 7;   // 0..3
    int col = nf * 16 + (lane & 15);
    int k0 = ks * 32 + (lane >> 4) * 8;
    bf16* dst = B2p + (size_t)idx * 8;
#pragma unroll
    for (int j = 0; j < 8; ++j) dst[j] = F2B(W2[(size_t)(k0 + j) * HID + col]);
}

// Wcomb for the epilogue GEMM: rows 0..255 = We2[u][c] = We[j][h*64+c] (u=h*64+j),
// rows 256..319 = Wskip[j][c].  Packed as [80][64] float4: Wc[l][(k>>2)*64+c][k&3].
__global__ void gt_prep_wcomb(const float* __restrict__ We, const float* __restrict__ Wskip,
                              float* __restrict__ Wc) {
    int idx = blockIdx.x * blockDim.x + threadIdx.x;
    if (idx >= NLAYERS * 320 * 64) return;
    int l = idx / (320 * 64);
    int r = idx % (320 * 64);
    int kk = r / 64;
    int c = r % 64;
    float val;
    if (kk < 256) {
        int hh = kk >> 6, j = kk & 63;
        val = We[(size_t)l * HID * HC + (size_t)j * HC + hh * 64 + c];
    } else {
        int j = kk - 256;
        val = Wskip[(size_t)l * HID * HID + (size_t)j * HID + c];
    }
    Wc[(size_t)l * 320 * 64 + (size_t)((kk >> 2) * 64 + c) * 4 + (kk & 3)] = val;
}

// ---------------- h = x @ node_W + node_b  (4 nodes/block) ----------------
__global__ void gt_node_proj(const float* __restrict__ x, const float* __restrict__ W,
                             const float* __restrict__ b, float* __restrict__ h) {
    int t = threadIdx.x;
    int n = blockIdx.x * 4 + (t >> 6);
    int c = t & 63;
    __shared__ float xr[4][NODE_DIM_];
    for (int i = t; i < 4 * NODE_DIM_; i += 256) {
        int nn = blockIdx.x * 4 + i / NODE_DIM_;
        xr[i / NODE_DIM_][i % NODE_DIM_] = (nn < NN) ? x[(size_t)nn * NODE_DIM_ + i % NODE_DIM_] : 0.f;
    }
    __syncthreads();
    if (n >= NN) return;
    float acc = 0.f;
#pragma unroll 8
    for (int j = 0; j < NODE_DIM_; ++j) acc += xr[t >> 6][j] * W[j * HID + c];
    h[(size_t)n * HID + c] = acc + b[c];
}

// ---------------- edge MLP: layer1 VALU (K=8) -> bf16 LDS, layer2 MFMA ----------------
__global__ void gt_edge_mlp(const float* __restrict__ ea, const float* __restrict__ W1,
                            const float* __restrict__ b1, const bf16* __restrict__ B2p,
                            const float* __restrict__ b2, bf16* __restrict__ ef) {
    int t = threadIdx.x;
    int c = t & 63, slot = t >> 6;
    int e0 = blockIdx.x * EB;
    __shared__ float aS[EB][EDGE_DIM_];
    __shared__ bf16 t1s[EB * 64];   // XOR-swizzled 16B units: unit u of row r at u^(r&7)
    for (int i = t; i < EB * EDGE_DIM_; i += 256) {
        ((float*)aS)[i] = ea[(size_t)e0 * EDGE_DIM_ + i];
    }
    float w1r[EDGE_DIM_];
#pragma unroll
    for (int j = 0; j < EDGE_DIM_; ++j) w1r[j] = W1[j * HID + c];
    float b1c = b1[c];
    __syncthreads();
    int cu = c >> 3, ci = c & 7;
#pragma unroll
    for (int es16 = 0; es16 < 16; ++es16) {
        int es = slot * 16 + es16;
        float acc = b1c;
#pragma unroll
        for (int j = 0; j < EDGE_DIM_; ++j) acc += aS[es][j] * w1r[j];
        int cs = ((cu ^ (es & 7)) << 3) | ci;
        t1s[es * 64 + cs] = F2B(fmaxf(acc, 0.f));
    }
    __syncthreads();
    int lane = t & 63, wave = slot;
    v8s bfr0 = *(const v8s*)(B2p + ((size_t)(wave * 2 + 0) * 64 + lane) * 8);
    v8s bfr1 = *(const v8s*)(B2p + ((size_t)(wave * 2 + 1) * 64 + lane) * 8);
    int rowA = lane & 15, kg = lane >> 4;
    f32x4 acc[4];
#pragma unroll
    for (int mf = 0; mf < 4; ++mf) acc[mf] = (f32x4){0.f, 0.f, 0.f, 0.f};
#pragma unroll
    for (int mf = 0; mf < 4; ++mf) {
        int r = mf * 16 + rowA;
        int u0 = 0 * 4 + kg, u1 = 1 * 4 + kg;
        v8s a0 = *(const v8s*)&t1s[r * 64 + ((u0 ^ (r & 7)) << 3)];
        v8s a1 = *(const v8s*)&t1s[r * 64 + ((u1 ^ (r & 7)) << 3)];
        acc[mf] = __builtin_amdgcn_mfma_f32_16x16x32_bf16(a0, bfr0, acc[mf], 0, 0, 0);
        acc[mf] = __builtin_amdgcn_mfma_f32_16x16x32_bf16(a1, bfr1, acc[mf], 0, 0, 0);
    }
    int col = wave * 16 + (lane & 15);
    float bb = b2[col];
    int rbase = (lane >> 4) * 4;
#pragma unroll
    for (int mf = 0; mf < 4; ++mf) {
#pragma unroll
        for (int reg = 0; reg < 4; ++reg) {
            int e = e0 + mf * 16 + rbase + reg;
            ef[(size_t)e * HID + col] = F2B(acc[mf][reg] + bb);
        }
    }
}

// ---------------- CSR build over dst ----------------
__global__ void gt_count_dst(const int* __restrict__ ei, int* cnt) {
    int e = blockIdx.x * blockDim.x + threadIdx.x;
    if (e < NE) {
        int d = clampi(ei[NE + e], 0, NN - 1);
        atomicAdd(&cnt[d], 1);
    }
}

__global__ void gt_scan_csr(const int* __restrict__ cnt, int* __restrict__ rp, int* __restrict__ cur) {
    __shared__ int part[256];
    int tid = threadIdx.x;
    const int CH = (NN + 255) / 256;
    int s0 = tid * CH, s1 = min(s0 + CH, NN);
    int s = 0;
    for (int i = s0; i < s1; ++i) s += cnt[i];
    part[tid] = s;
    __syncthreads();
    for (int off = 1; off < 256; off <<= 1) {
        int vv = (tid >= off) ? part[tid - off] : 0;
        __syncthreads();
        if (tid >= off) part[tid] += vv;
        __syncthreads();
    }
    int base = (tid == 0) ? 0 : part[tid - 1];
    for (int i = s0; i < s1; ++i) {
        rp[i] = base;
        cur[i] = base;
        base += cnt[i];
    }
    if (tid == 255) rp[NN] = part[255];
}

__global__ void gt_fill_csr(const int* __restrict__ ei, int* cur, int* csr) {
    int e = blockIdx.x * blockDim.x + threadIdx.x;
    if (e < NE) {
        int d = clampi(ei[NE + e], 0, NN - 1);
        int pos = atomicAdd(&cur[d], 1);
        if (pos >= 0 && pos < NE) csr[pos] = e;
    }
}

// ---------------- fused q|k|v|qe projection: [20000x64] @ [64x1024] via MFMA ----------
// M-tile = 16 (1250 blocks).  Wave w owns cols [w*256,(w+1)*256):
// w=0 -> q (fp32), 1 -> k (into interleaved kv), 2 -> v (into kv), 3 -> qe (bf16).
// kv layout: row n = 512 bf16; unit g (=c>>2) holds k[4g..4g+3] then v[4g..4g+3].
__global__ void __launch_bounds__(256)
gt_qkv_mfma(const float* __restrict__ h, const bf16* __restrict__ Bp,
            const float* __restrict__ bias4,
            float* __restrict__ q, bf16* __restrict__ kv, bf16* __restrict__ qe) {
    int t = threadIdx.x, lane = t & 63, wave = t >> 6;
    int n0 = blockIdx.x * 16;
    int rowA = lane & 15, kg = lane >> 4;

    v8s a[2];
    {
        const float* hr = h + (size_t)(n0 + rowA) * HID;
#pragma unroll
        for (int ks = 0; ks < 2; ++ks) {
            const float* p = hr + ks * 32 + kg * 8;
            float4 x0 = *(const float4*)p;
            float4 x1 = *(const float4*)(p + 4);
            v8s av;
            av[0] = F2BS(x0.x); av[1] = F2BS(x0.y); av[2] = F2BS(x0.z); av[3] = F2BS(x0.w);
            av[4] = F2BS(x1.x); av[5] = F2BS(x1.y); av[6] = F2BS(x1.z); av[7] = F2BS(x1.w);
            a[ks] = av;
        }
    }

    f32x4 acc[16];
#pragma unroll
    for (int nf = 0; nf < 16; ++nf) acc[nf] = (f32x4){0.f, 0.f, 0.f, 0.f};

#pragma unroll
    for (int nf = 0; nf < 16; ++nf) {
        int nfg = wave * 16 + nf;
        v8s b0 = *(const v8s*)(Bp + ((size_t)(nfg * 2 + 0) * 64 + lane) * 8);
        v8s b1 = *(const v8s*)(Bp + ((size_t)(nfg * 2 + 1) * 64 + lane) * 8);
        acc[nf] = __builtin_amdgcn_mfma_f32_16x16x32_bf16(a[0], b0, acc[nf], 0, 0, 0);
        acc[nf] = __builtin_amdgcn_mfma_f32_16x16x32_bf16(a[1], b1, acc[nf], 0, 0, 0);
    }

    int rbase = (lane >> 4) * 4;
#pragma unroll
    for (int nf = 0; nf < 16; ++nf) {
        int cc = nf * 16 + (lane & 15);
        float bias = bias4[wave * 256 + cc];
#pragma unroll
        for (int reg = 0; reg < 4; ++reg) {
            int n = n0 + rbase + reg;
            float val = acc[nf][reg] + bias;
            if (wave == 0)      q [(size_t)n * HC + cc] = val;
            else if (wave == 1) kv[(size_t)n * 512 + ((cc >> 2) << 3) + (cc & 3)] = F2B(val);
            else if (wave == 2) kv[(size_t)n * 512 + ((cc >> 2) << 3) + 4 + (cc & 3)] = F2B(val);
            else                qe[(size_t)n * HC + cc] = F2B(val);
        }
    }
}

// ---------------- attention core: wave-per-node (degree-sorted), kv-interleaved ----
// Node assignment via perm[] (degree-descending): the 4 nodes of a block have
// near-equal degree -> block no longer waits on a straggler wave.
// lane l owns channels 4l..4l+3.  kv row: unit l = [k0..k3 v0..v3] -> ONE dwordx4
// gather per edge.  A/B pair double-buffer (step 4).  Defer-max softmax (THR=8).
// Outputs: normalized acc_s -> q row (in place), head-mean acc_v -> vm[N][64].
__global__ void gt_attn_core(float* __restrict__ q, const bf16* __restrict__ qe,
                             const bf16* __restrict__ kv, const bf16* __restrict__ ef,
                             const int* __restrict__ rp, const int* __restrict__ csr,
                             const int* __restrict__ ei, const int* __restrict__ perm,
                             float* __restrict__ vm) {
    int t = threadIdx.x;
    int lane = t & 63, wave = t >> 6;
    int slot = blockIdx.x * 4 + wave;
    if (slot >= NN) return;
    int n = clampi(perm[slot], 0, NN - 1);

    const float4* q4 = (const float4*)q;
    const ushort4* qe4 = (const ushort4*)qe;  // 64 units of 8B per row
    const u16x8* kv8 = (const u16x8*)kv;      // 64 units per row
    const ushort4* e4p = (const ushort4*)ef;
    int elane = lane & 15;

    float4 qv = q4[(size_t)n * 64 + lane];
    ushort4 qeu = qe4[(size_t)n * 64 + lane];
    float4 qev = make_float4(U2F(qeu.x), U2F(qeu.y), U2F(qeu.z), U2F(qeu.w));

    int s0 = clampi(rp[n], 0, NE), s1 = clampi(rp[n + 1], s0, NE);
    float m = -1e30f, lr = 0.f;
    float4 accv = make_float4(0.f, 0.f, 0.f, 0.f);
    float4 accs = make_float4(0.f, 0.f, 0.f, 0.f);

    auto process = [&](u16x8 k0, ushort4 f0, u16x8 k1, ushort4 f1, bool ok0, bool ok1) {
        float p0 = qv.x * U2F(k0[0]) + qv.y * U2F(k0[1]) + qv.z * U2F(k0[2]) + qv.w * U2F(k0[3])
                 + qev.x * U2F(f0.x) + qev.y * U2F(f0.y) + qev.z * U2F(f0.z) + qev.w * U2F(f0.w);
        float p1 = qv.x * U2F(k1[0]) + qv.y * U2F(k1[1]) + qv.z * U2F(k1[2]) + qv.w * U2F(k1[3])
                 + qev.x * U2F(f1.x) + qev.y * U2F(f1.y) + qev.z * U2F(f1.z) + qev.w * U2F(f1.w);
        p0 += __shfl_xor(p0, 8, 16);  p1 += __shfl_xor(p1, 8, 16);
        p0 += __shfl_xor(p0, 4, 16);  p1 += __shfl_xor(p1, 4, 16);
        p0 += __shfl_xor(p0, 2, 16);  p1 += __shfl_xor(p1, 2, 16);
        p0 += __shfl_xor(p0, 1, 16);  p1 += __shfl_xor(p1, 1, 16);
        p0 = ok0 ? p0 * 0.125f : -1e30f;
        p1 = ok1 ? p1 * 0.125f : -1e30f;
        float pm = fmaxf(p0, p1);
        if (__any(pm - m > 8.f)) {
            float nm = fmaxf(m, pm);
            float sc = __expf(m - nm);
            m = nm;
            lr *= sc;
            accv.x *= sc; accv.y *= sc; accv.z *= sc; accv.w *= sc;
            accs.x *= sc; accs.y *= sc; accs.z *= sc; accs.w *= sc;
        }
        float w0 = __expf(p0 - m);
        float w1 = __expf(p1 - m);
        lr += w0 + w1;
        accv.x += w0 * U2F(k0[4]) + w1 * U2F(k1[4]);
        accv.y += w0 * U2F(k0[5]) + w1 * U2F(k1[5]);
        accv.z += w0 * U2F(k0[6]) + w1 * U2F(k1[6]);
        accv.w += w0 * U2F(k0[7]) + w1 * U2F(k1[7]);
        accs.x += w0 * U2F(f0.x) + w1 * U2F(f1.x);
        accs.y += w0 * U2F(f0.y) + w1 * U2F(f1.y);
        accs.z += w0 * U2F(f0.z) + w1 * U2F(f1.z);
        accs.w += w0 * U2F(f0.w) + w1 * U2F(f1.w);
    };

    for (int base = s0; base < s1; base += 64) {
        int cnt = min(64, s1 - base);
        int eL = 0, srcL = 0;
        if (lane < cnt) {
            eL = clampi(csr[base + lane], 0, NE - 1);
            srcL = clampi(ei[eL], 0, NN - 1);
        }
        // preload pair A = edges 0,1 (clamped)
        int jb = min(1, cnt - 1);
        int eA0 = __builtin_amdgcn_readlane(eL, 0), rA0 = __builtin_amdgcn_readlane(srcL, 0);
        int eA1 = __builtin_amdgcn_readlane(eL, jb), rA1 = __builtin_amdgcn_readlane(srcL, jb);
        u16x8 kvA0 = kv8[(size_t)rA0 * 64 + lane];
        u16x8 kvA1 = kv8[(size_t)rA1 * 64 + lane];
        ushort4 efA0 = e4p[(size_t)eA0 * 16 + elane];
        ushort4 efA1 = e4p[(size_t)eA1 * 16 + elane];
        u16x8 kvB0, kvB1;
        ushort4 efB0, efB1;
        for (int i = 0; i < cnt; i += 4) {
            // issue loads for pair B = edges i+2, i+3 (clamped)
            {
                int j2 = min(i + 2, cnt - 1), j3 = min(i + 3, cnt - 1);
                int e2 = __builtin_amdgcn_readlane(eL, j2), r2 = __builtin_amdgcn_readlane(srcL, j2);
                int e3 = __builtin_amdgcn_readlane(eL, j3), r3 = __builtin_amdgcn_readlane(srcL, j3);
                kvB0 = kv8[(size_t)r2 * 64 + lane];
                kvB1 = kv8[(size_t)r3 * 64 + lane];
                efB0 = e4p[(size_t)e2 * 16 + elane];
                efB1 = e4p[(size_t)e3 * 16 + elane];
            }
            process(kvA0, efA0, kvA1, efA1, true, i + 1 < cnt);
            // issue loads for next pair A = edges i+4, i+5 (clamped)
            if (i + 4 < cnt) {
                int j4 = i + 4, j5 = min(i + 5, cnt - 1);
                int e4 = __builtin_amdgcn_readlane(eL, j4), r4 = __builtin_amdgcn_readlane(srcL, j4);
                int e5 = __builtin_amdgcn_readlane(eL, j5), r5 = __builtin_amdgcn_readlane(srcL, j5);
                kvA0 = kv8[(size_t)r4 * 64 + lane];
                kvA1 = kv8[(size_t)r5 * 64 + lane];
                efA0 = e4p[(size_t)e4 * 16 + elane];
                efA1 = e4p[(size_t)e5 * 16 + elane];
            }
            if (i + 2 < cnt) {
                process(kvB0, efB0, kvB1, efB1, true, i + 3 < cnt);
            }
        }
    }
    float inv = (s1 > s0) ? 0.25f / lr : 0.f;   // fold mean-over-heads 0.25
    float4 rs = make_float4(accs.x * inv, accs.y * inv, accs.z * inv, accs.w * inv);
    ((float4*)q)[(size_t)n * 64 + lane] = rs;
    float4 rv = make_float4(accv.x * inv, accv.y * inv, accv.z * inv, accv.w * inv);
    rv.x += __shfl_xor(rv.x, 16, 64); rv.x += __shfl_xor(rv.x, 32, 64);
    rv.y += __shfl_xor(rv.y, 16, 64); rv.y += __shfl_xor(rv.y, 32, 64);
    rv.z += __shfl_xor(rv.z, 16, 64); rv.z += __shfl_xor(rv.z, 32, 64);
    rv.w += __shfl_xor(rv.w, 16, 64); rv.w += __shfl_xor(rv.w, 32, 64);
    if (lane < 16) ((float4*)vm)[(size_t)n * 16 + lane] = rv;
}

// ---------------- epilogue: batched [16 x 320] @ [320 x 64] + vm + res + bskip, LN, ReLU ----------------
// acc_s = q (rows [N][256] = normalized alpha-weighted ef sums)
// acc_vm = vm (dense [N][64] fp32 head-mean of alpha-weighted v)
__global__ void gt_epilogue(const float* __restrict__ acc_s, const float* __restrict__ acc_vm,
                            const float* __restrict__ Wc, const float* __restrict__ bskip,
                            const float* __restrict__ lng, const float* __restrict__ lnb,
                            float* __restrict__ h) {
    int t = threadIdx.x;
    int c = t & 63, qw = t >> 6;
    int n0 = blockIdx.x * EPB;
    __shared__ float sK[EPB][320];   // cols 0..255: acc_s, cols 256..319: res (h)
    __shared__ float sVM[EPB][64];
    const float4* as4 = (const float4*)acc_s;
    for (int i = t; i < EPB * 64; i += 256) {
        int nd = i >> 6, j4 = i & 63;
        *(float4*)&sK[nd][4 * j4] = as4[(size_t)(n0 + nd) * 64 + j4];
    }
    const float4* h4g = (const float4*)h;
    const float4* vm4 = (const float4*)acc_vm;   // 16 float4 per row
    for (int i = t; i < EPB * 16; i += 256) {
        int nd = i >> 4, j4 = i & 15;
        *(float4*)&sK[nd][256 + 4 * j4] = h4g[(size_t)(n0 + nd) * 16 + j4];
        *(float4*)&sVM[nd][4 * j4] = vm4[(size_t)(n0 + nd) * 16 + j4];
    }
    __syncthreads();
    int nb = qw * 4;
    const float4* r0 = (const float4*)&sK[nb][0];
    const float4* r1 = (const float4*)&sK[nb + 1][0];
    const float4* r2 = (const float4*)&sK[nb + 2][0];
    const float4* r3 = (const float4*)&sK[nb + 3][0];
    const float4* W4 = (const float4*)Wc;
    float a0 = 0.f, a1 = 0.f, a2 = 0.f, a3 = 0.f;
#pragma unroll 4
    for (int k4 = 0; k4 < 80; ++k4) {
        float4 w = W4[k4 * 64 + c];
        float4 x0 = r0[k4]; a0 += x0.x * w.x + x0.y * w.y + x0.z * w.z + x0.w * w.w;
        float4 x1 = r1[k4]; a1 += x1.x * w.x + x1.y * w.y + x1.z * w.z + x1.w * w.w;
        float4 x2 = r2[k4]; a2 += x2.x * w.x + x2.y * w.y + x2.z * w.z + x2.w * w.w;
        float4 x3 = r3[k4]; a3 += x3.x * w.x + x3.y * w.y + x3.z * w.z + x3.w * w.w;
    }
    float bsk = bskip[c], g = lng[c], bb = lnb[c];
    float y0 = a0 + sVM[nb][c] + sK[nb][256 + c] + bsk;
    float y1 = a1 + sVM[nb + 1][c] + sK[nb + 1][256 + c] + bsk;
    float y2 = a2 + sVM[nb + 2][c] + sK[nb + 2][256 + c] + bsk;
    float y3 = a3 + sVM[nb + 3][c] + sK[nb + 3][256 + c] + bsk;
    float m0 = y0, m1 = y1, m2 = y2, m3 = y3;
#pragma unroll
    for (int s = 32; s > 0; s >>= 1) {
        m0 += __shfl_xor(m0, s, 64);
        m1 += __shfl_xor(m1, s, 64);
        m2 += __shfl_xor(m2, s, 64);
        m3 += __shfl_xor(m3, s, 64);
    }
    m0 *= (1.f / HID); m1 *= (1.f / HID); m2 *= (1.f / HID); m3 *= (1.f / HID);
    float d0 = y0 - m0, d1 = y1 - m1, d2 = y2 - m2, d3 = y3 - m3;
    float v0 = d0 * d0, v1 = d1 * d1, v2 = d2 * d2, v3 = d3 * d3;
#pragma unroll
    for (int s = 32; s > 0; s >>= 1) {
        v0 += __shfl_xor(v0, s, 64);
        v1 += __shfl_xor(v1, s, 64);
        v2 += __shfl_xor(v2, s, 64);
        v3 += __shfl_xor(v3, s, 64);
    }
    v0 *= (1.f / HID); v1 *= (1.f / HID); v2 *= (1.f / HID); v3 *= (1.f / HID);
    h[(size_t)(n0 + nb) * HID + c]     = fmaxf(d0 * rsqrtf(v0 + 1e-5f) * g + bb, 0.f);
    h[(size_t)(n0 + nb + 1) * HID + c] = fmaxf(d1 * rsqrtf(v1 + 1e-5f) * g + bb, 0.f);
    h[(size_t)(n0 + nb + 2) * HID + c] = fmaxf(d2 * rsqrtf(v2 + 1e-5f) * g + bb, 0.f);
    h[(size_t)(n0 + nb + 3) * HID + c] = fmaxf(d3 * rsqrtf(v3 + 1e-5f) * g + bb, 0.f);
}

// ---------------- pool stage 1: segment partial sums + atomics (batch sorted) ----------------
__global__ void gt_pool_sum(const float* __restrict__ h, const int* __restrict__ batch,
                            float* __restrict__ psum) {
    int t = threadIdx.x;
    int c = t & 63, slot = t >> 6;
    int n0 = blockIdx.x * 256;
    float acc = 0.f;
    int curg = -1;
    for (int i = slot; i < 256; i += 4) {
        int n = n0 + i;
        if (n >= NN) break;
        int g = clampi(batch[n], 0, NGRAPHS - 1);
        float val = h[(size_t)n * HID + c];
        if (g != curg) {
            if (curg >= 0) atomicAdd(&psum[curg * HID + c], acc);
            curg = g;
            acc = 0.f;
        }
        acc += val;
    }
    if (curg >= 0) atomicAdd(&psum[curg * HID + c], acc);
}

// ---------------- pool stage 2: divide by true count + classifier ----------------
__global__ void gt_classify(const float* __restrict__ psum, const int* __restrict__ batch,
                            const float* __restrict__ W, const float* __restrict__ b,
                            float* __restrict__ out) {
    int g = blockIdx.x;
    int c = threadIdx.x;
    __shared__ float pooled[HID];
    __shared__ float lg[4];
    __shared__ int bounds[2];
    if (c < 2) {
        int target = g + c;
        int lo = 0, hi = NN;
        while (lo < hi) {
            int mid = (lo + hi) >> 1;
            if (batch[mid] < target) lo = mid + 1; else hi = mid;
        }
        bounds[c] = lo;
    }
    __syncthreads();
    float divf = fmaxf((float)(bounds[1] - bounds[0]), 1.f);
    pooled[c] = psum[g * HID + c] / divf;
    __syncthreads();
    if (c < NCLASSES) {
        float acc = 0.f;
        for (int j = 0; j < HID; ++j) acc += pooled[j] * W[j * NCLASSES + c];
        lg[c] = acc + b[c];
    }
    __syncthreads();
    if (c == 0) {
        float m = fmaxf(lg[0], fmaxf(lg[1], lg[2]));
        float ssum = 0.f;
        for (int cc = 0; cc < NCLASSES; ++cc) ssum += __expf(lg[cc] - m);
        float lse = logf(ssum);
        for (int cc = 0; cc < NCLASSES; ++cc) out[g * NCLASSES + cc] = lg[cc] - m - lse;
    }
}

extern "C" void kernel_launch(void* const* d_in, const int* in_sizes, int n_in,
                              void* d_out, int out_size, void* d_ws, size_t ws_size,
                              hipStream_t stream) {
    float* out = (float*)d_out;

    static const int EXPECT[23] = {2560000, 2048000, 8192, 64, 512, 64, 4096, 64,
                                   49152, 768, 49152, 768, 49152, 768, 49152,
                                   12288, 192, 192, 192, 192, 3, 512000, 20000};
    int bad = -1;
    if (n_in != 23) bad = 99;
    else {
        for (int i = 0; i < 23; ++i) {
            if (in_sizes[i] != EXPECT[i]) { bad = i; break; }
        }
    }
    if (bad >= 0) {
        float val = (bad == 99) ? 4000.f : (5000.f + 10.f * bad);
        gt_write_const<<<1, 256, 0, stream>>>(out, out_size, val);
        return;
    }

    const float* x        = (const float*)d_in[0];
    const float* edge_attr= (const float*)d_in[1];
    const float* node_W   = (const float*)d_in[2];
    const float* node_b   = (const float*)d_in[3];
    const float* e1_W     = (const float*)d_in[4];
    const float* e1_b     = (const float*)d_in[5];
    const float* e2_W     = (const float*)d_in[6];
    const float* e2_b     = (const float*)d_in[7];
    const float* Wq       = (const float*)d_in[8];
    const float* bq       = (const float*)d_in[9];
    const float* Wk       = (const float*)d_in[10];
    const float* bk       = (const float*)d_in[11];
    const float* Wv       = (const float*)d_in[12];
    const float* bv       = (const float*)d_in[13];
    const float* We       = (const float*)d_in[14];
    const float* Wskip    = (const float*)d_in[15];
    const float* bskip    = (const float*)d_in[16];
    const float* lng      = (const float*)d_in[17];
    const float* lnb      = (const float*)d_in[18];
    const float* cls_W    = (const float*)d_in[19];
    const float* cls_b    = (const float*)d_in[20];
    const int*   ei       = (const int*)d_in[21];
    const int*   batch    = (const int*)d_in[22];

    char* w = (char*)d_ws;
    auto alloc = [&](size_t bytes) -> char* {
        char* p = w;
        w += (bytes + 255) & ~(size_t)255;
        return p;
    };
    float* h     = (float*)alloc((size_t)NN * HID * 4);
    bf16*  ef    = (bf16*)alloc((size_t)NE * HID * 2);
    float* q     = (float*)alloc((size_t)NN * HC * 4);
    bf16*  kv    = (bf16*)alloc((size_t)NN * 512 * 2);
    bf16*  qe    = (bf16*)alloc((size_t)NN * HC * 2);
    float* vm    = (float*)alloc((size_t)NN * HID * 4);
    float* Wqe   = (float*)alloc((size_t)NLAYERS * HID * HC * 4);
    float* bias4 = (float*)alloc((size_t)NLAYERS * 1024 * 4);
    bf16*  Bp    = (bf16*)alloc((size_t)NLAYERS * 8192 * 8 * 2);
    bf16*  B2p   = (bf16*)alloc((size_t)512 * 8 * 2);
    float* Wc    = (float*)alloc((size_t)NLAYERS * 320 * 64 * 4);
    float* psum  = (float*)alloc((size_t)NGRAPHS * HID * 4);
    int*   cnt   = (int*)alloc((size_t)NN * 4);
    int*   rp    = (int*)alloc((size_t)(NN + 1) * 4);
    int*   cur   = (int*)alloc((size_t)NN * 4);
    int*   csr   = (int*)alloc((size_t)NE * 4);
    int*   perm  = (int*)alloc((size_t)NN * 4);
    int*   bins  = (int*)alloc((size_t)256 * 4);
    int*   boff  = (int*)alloc((size_t)256 * 4);

    gt_node_proj<<<(NN + 3) / 4, 256, 0, stream>>>(x, node_W, node_b, h);
    gt_prep_wqe<<<NLAYERS * 65, 256, 0, stream>>>(Wq, bq, bk, bv, We, Wqe, bias4);
    gt_pack_qkv<<<(NLAYERS * 8192 + 255) / 256, 256, 0, stream>>>(Wq, Wk, Wv, Wqe, Bp);
    gt_pack_w2<<<2, 256, 0, stream>>>(e2_W, B2p);
    gt_edge_mlp<<<NE / EB, 256, 0, stream>>>(edge_attr, e1_W, e1_b, B2p, e2_b, ef);
    gt_prep_wcomb<<<(NLAYERS * 320 * 64 + 255) / 256, 256, 0, stream>>>(We, Wskip, Wc);
    gt_zero_i32<<<(NN + 255) / 256, 256, 0, stream>>>(cnt, NN);
    gt_count_dst<<<(NE + 255) / 256, 256, 0, stream>>>(ei, cnt);
    gt_scan_csr<<<1, 256, 0, stream>>>(cnt, rp, cur);
    gt_fill_csr<<<(NE + 255) / 256, 256, 0, stream>>>(ei, cur, csr);
    gt_zero_i32<<<1, 256, 0, stream>>>(bins, 256);
    gt_deg_hist<<<(NN + 255) / 256, 256, 0, stream>>>(cnt, bins);
    gt_deg_scan<<<1, 256, 0, stream>>>(bins, boff);
    gt_deg_scatter<<<(NN + 255) / 256, 256, 0, stream>>>(cnt, boff, perm);

    for (int l = 0; l < NLAYERS; ++l) {
        const bf16* Bp_l  = Bp + (size_t)l * 8192 * 8;
        const float* b4_l = bias4 + (size_t)l * 1024;
        const float* Wc_l = Wc + (size_t)l * 320 * 64;
        const float* bs_l = bskip + (size_t)l * HID;
        const float* lg_l = lng + (size_t)l * HID;
        const float* lb_l = lnb + (size_t)l * HID;

        gt_qkv_mfma<<<NN / 16, 256, 0, stream>>>(h, Bp_l, b4_l, q, kv, qe);
        gt_attn_core<<<(NN + 3) / 4, 256, 0, stream>>>(q, qe, kv, ef, rp, csr, ei, perm, vm);
        gt_epilogue<<<NN / EPB, 256, 0, stream>>>(q, vm, Wc_l, bs_l, lg_l, lb_l, h);
    }

    gt_zero_i32<<<(NGRAPHS * HID + 255) / 256, 256, 0, stream>>>((int*)psum, NGRAPHS * HID);
    gt_pool_sum<<<(NN + 255) / 256, 256, 0, stream>>>(h, batch, psum);
    gt_classify<<<NGRAPHS, HID, 0, stream>>>(psum, batch, cls_W, cls_b, out);
}

// Round 12
// 592.233 us; speedup vs baseline: 1.1560x; 1.1560x over previous
//
#include <hip/hip_runtime.h>
#include <hip/hip_bf16.h>
#include <math.h>

#define NN 20000
#define NE 256000
#define NODE_DIM_ 128
#define EDGE_DIM_ 8
#define HID 64
#define HEADS 4
#define NLAYERS 3
#define NCLASSES 3
#define NGRAPHS 64
#define HC 256  // HEADS*HID
#define EB 64   // edges per block in edge_mlp
#define EPB 16  // nodes per block in epilogue

typedef __hip_bfloat16 bf16;
using v8s = __attribute__((ext_vector_type(8))) short;
using u16x8 = __attribute__((ext_vector_type(8))) unsigned short;
using f32x4 = __attribute__((ext_vector_type(4))) float;

__device__ __forceinline__ float B2F(bf16 x) { return __bfloat162float(x); }
__device__ __forceinline__ bf16 F2B(float x) { return __float2bfloat16(x); }
__device__ __forceinline__ short F2BS(float x) {
    union { bf16 b; short s; } u; u.b = __float2bfloat16(x); return u.s;
}
__device__ __forceinline__ float U2F(unsigned short u) { return __uint_as_float(((unsigned)u) << 16); }
__device__ __forceinline__ int clampi(int x, int lo, int hi) { return min(max(x, lo), hi); }

// ---------------- diagnostics ----------------
__global__ void gt_write_const(float* out, int n, float val) {
    int i = blockIdx.x * blockDim.x + threadIdx.x;
    if (i < n) out[i] = val;
}

// ---------------- utility ----------------
__global__ void gt_zero_i32(int* p, int n) {
    int i = blockIdx.x * blockDim.x + threadIdx.x;
    if (i < n) p[i] = 0;
}

// ---------------- Wqe = Wq-head @ We-head (fused qe weight) + bias4 ----------------
__global__ void gt_prep_wqe(const float* __restrict__ Wq, const float* __restrict__ bq,
                            const float* __restrict__ bk, const float* __restrict__ bv,
                            const float* __restrict__ We,
                            float* __restrict__ Wqe, float* __restrict__ bias4) {
    int b = blockIdx.x;
    int l = b / 65, kk = b % 65;
    int t = threadIdx.x;
    int hh = t >> 6, d = t & 63;
    const float* Weh = We + (size_t)l * HID * HC + (size_t)d * HC + hh * 64;
    if (kk < 64) {
        const float* Wqr = Wq + (size_t)l * HID * HC + (size_t)kk * HC + hh * 64;
        float s = 0.f;
        for (int c = 0; c < 64; ++c) s += Wqr[c] * Weh[c];
        Wqe[(size_t)l * HID * HC + (size_t)kk * HC + t] = s;
    } else {
        const float* bqr = bq + (size_t)l * HC + hh * 64;
        float s = 0.f;
        for (int c = 0; c < 64; ++c) s += bqr[c] * Weh[c];
        bias4[(size_t)l * 1024 + 768 + t] = s;
        bias4[(size_t)l * 1024 + t]       = bq[(size_t)l * HC + t];
        bias4[(size_t)l * 1024 + 256 + t] = bk[(size_t)l * HC + t];
        bias4[(size_t)l * 1024 + 512 + t] = bv[(size_t)l * HC + t];
    }
}

// ---------------- pack W4 = [Wq|Wk|Wv|Wqe] (64 x 1024) into per-fragment bf16 layout ----
__global__ void gt_pack_qkv(const float* __restrict__ Wq, const float* __restrict__ Wk,
                            const float* __restrict__ Wv, const float* __restrict__ Wqe,
                            bf16* __restrict__ Bp) {
    int idx = blockIdx.x * 256 + threadIdx.x;
    if (idx >= NLAYERS * 8192) return;
    int lane = idx & 63;
    int ks = (idx >> 6) & 1;
    int nf = (idx >> 7) & 63;
    int l = idx >> 13;
    int col = nf * 16 + (lane & 15);
    int k0 = ks * 32 + (lane >> 4) * 8;
    const float* src;
    int c;
    if (col < 256)      { src = Wq  + (size_t)l * HID * HC; c = col; }
    else if (col < 512) { src = Wk  + (size_t)l * HID * HC; c = col - 256; }
    else if (col < 768) { src = Wv  + (size_t)l * HID * HC; c = col - 512; }
    else                { src = Wqe + (size_t)l * HID * HC; c = col - 768; }
    bf16* dst = Bp + (size_t)idx * 8;
#pragma unroll
    for (int j = 0; j < 8; ++j) dst[j] = F2B(src[(size_t)(k0 + j) * HC + c]);
}

// ---------------- pack W2 (64x64) into fragment layout ----------------
__global__ void gt_pack_w2(const float* __restrict__ W2, bf16* __restrict__ B2p) {
    int idx = blockIdx.x * 256 + threadIdx.x;
    if (idx >= 512) return;
    int lane = idx & 63;
    int ks = (idx >> 6) & 1;
    int nf = idx >> 7;   // 0..3
    int col = nf * 16 + (lane & 15);
    int k0 = ks * 32 + (lane >> 4) * 8;
    bf16* dst = B2p + (size_t)idx * 8;
#pragma unroll
    for (int j = 0; j < 8; ++j) dst[j] = F2B(W2[(size_t)(k0 + j) * HID + col]);
}

// Wcomb for the epilogue GEMM: rows 0..255 = We2[u][c] = We[j][h*64+c] (u=h*64+j),
// rows 256..319 = Wskip[j][c].  Packed as [80][64] float4: Wc[l][(k>>2)*64+c][k&3].
__global__ void gt_prep_wcomb(const float* __restrict__ We, const float* __restrict__ Wskip,
                              float* __restrict__ Wc) {
    int idx = blockIdx.x * blockDim.x + threadIdx.x;
    if (idx >= NLAYERS * 320 * 64) return;
    int l = idx / (320 * 64);
    int r = idx % (320 * 64);
    int kk = r / 64;
    int c = r % 64;
    float val;
    if (kk < 256) {
        int hh = kk >> 6, j = kk & 63;
        val = We[(size_t)l * HID * HC + (size_t)j * HC + hh * 64 + c];
    } else {
        int j = kk - 256;
        val = Wskip[(size_t)l * HID * HID + (size_t)j * HID + c];
    }
    Wc[(size_t)l * 320 * 64 + (size_t)((kk >> 2) * 64 + c) * 4 + (kk & 3)] = val;
}

// ---------------- h = x @ node_W + node_b  (4 nodes/block) ----------------
__global__ void gt_node_proj(const float* __restrict__ x, const float* __restrict__ W,
                             const float* __restrict__ b, float* __restrict__ h) {
    int t = threadIdx.x;
    int n = blockIdx.x * 4 + (t >> 6);
    int c = t & 63;
    __shared__ float xr[4][NODE_DIM_];
    for (int i = t; i < 4 * NODE_DIM_; i += 256) {
        int nn = blockIdx.x * 4 + i / NODE_DIM_;
        xr[i / NODE_DIM_][i % NODE_DIM_] = (nn < NN) ? x[(size_t)nn * NODE_DIM_ + i % NODE_DIM_] : 0.f;
    }
    __syncthreads();
    if (n >= NN) return;
    float acc = 0.f;
#pragma unroll 8
    for (int j = 0; j < NODE_DIM_; ++j) acc += xr[t >> 6][j] * W[j * HID + c];
    h[(size_t)n * HID + c] = acc + b[c];
}

// ---------------- edge MLP: layer1 VALU (K=8) -> bf16 LDS, layer2 MFMA ----------------
__global__ void gt_edge_mlp(const float* __restrict__ ea, const float* __restrict__ W1,
                            const float* __restrict__ b1, const bf16* __restrict__ B2p,
                            const float* __restrict__ b2, bf16* __restrict__ ef) {
    int t = threadIdx.x;
    int c = t & 63, slot = t >> 6;
    int e0 = blockIdx.x * EB;
    __shared__ float aS[EB][EDGE_DIM_];
    __shared__ bf16 t1s[EB * 64];   // XOR-swizzled 16B units: unit u of row r at u^(r&7)
    for (int i = t; i < EB * EDGE_DIM_; i += 256) {
        ((float*)aS)[i] = ea[(size_t)e0 * EDGE_DIM_ + i];
    }
    float w1r[EDGE_DIM_];
#pragma unroll
    for (int j = 0; j < EDGE_DIM_; ++j) w1r[j] = W1[j * HID + c];
    float b1c = b1[c];
    __syncthreads();
    int cu = c >> 3, ci = c & 7;
#pragma unroll
    for (int es16 = 0; es16 < 16; ++es16) {
        int es = slot * 16 + es16;
        float acc = b1c;
#pragma unroll
        for (int j = 0; j < EDGE_DIM_; ++j) acc += aS[es][j] * w1r[j];
        int cs = ((cu ^ (es & 7)) << 3) | ci;
        t1s[es * 64 + cs] = F2B(fmaxf(acc, 0.f));
    }
    __syncthreads();
    int lane = t & 63, wave = slot;
    v8s bfr0 = *(const v8s*)(B2p + ((size_t)(wave * 2 + 0) * 64 + lane) * 8);
    v8s bfr1 = *(const v8s*)(B2p + ((size_t)(wave * 2 + 1) * 64 + lane) * 8);
    int rowA = lane & 15, kg = lane >> 4;
    f32x4 acc[4];
#pragma unroll
    for (int mf = 0; mf < 4; ++mf) acc[mf] = (f32x4){0.f, 0.f, 0.f, 0.f};
#pragma unroll
    for (int mf = 0; mf < 4; ++mf) {
        int r = mf * 16 + rowA;
        int u0 = 0 * 4 + kg, u1 = 1 * 4 + kg;
        v8s a0 = *(const v8s*)&t1s[r * 64 + ((u0 ^ (r & 7)) << 3)];
        v8s a1 = *(const v8s*)&t1s[r * 64 + ((u1 ^ (r & 7)) << 3)];
        acc[mf] = __builtin_amdgcn_mfma_f32_16x16x32_bf16(a0, bfr0, acc[mf], 0, 0, 0);
        acc[mf] = __builtin_amdgcn_mfma_f32_16x16x32_bf16(a1, bfr1, acc[mf], 0, 0, 0);
    }
    int col = wave * 16 + (lane & 15);
    float bb = b2[col];
    int rbase = (lane >> 4) * 4;
#pragma unroll
    for (int mf = 0; mf < 4; ++mf) {
#pragma unroll
        for (int reg = 0; reg < 4; ++reg) {
            int e = e0 + mf * 16 + rbase + reg;
            ef[(size_t)e * HID + col] = F2B(acc[mf][reg] + bb);
        }
    }
}

// ---------------- CSR build over dst ----------------
__global__ void gt_count_dst(const int* __restrict__ ei, int* cnt) {
    int e = blockIdx.x * blockDim.x + threadIdx.x;
    if (e < NE) {
        int d = clampi(ei[NE + e], 0, NN - 1);
        atomicAdd(&cnt[d], 1);
    }
}

__global__ void gt_scan_csr(const int* __restrict__ cnt, int* __restrict__ rp, int* __restrict__ cur) {
    __shared__ int part[256];
    int tid = threadIdx.x;
    const int CH = (NN + 255) / 256;
    int s0 = tid * CH, s1 = min(s0 + CH, NN);
    int s = 0;
    for (int i = s0; i < s1; ++i) s += cnt[i];
    part[tid] = s;
    __syncthreads();
    for (int off = 1; off < 256; off <<= 1) {
        int vv = (tid >= off) ? part[tid - off] : 0;
        __syncthreads();
        if (tid >= off) part[tid] += vv;
        __syncthreads();
    }
    int base = (tid == 0) ? 0 : part[tid - 1];
    for (int i = s0; i < s1; ++i) {
        rp[i] = base;
        cur[i] = base;
        base += cnt[i];
    }
    if (tid == 255) rp[NN] = part[255];
}

__global__ void gt_fill_csr(const int* __restrict__ ei, int* cur, int* csr) {
    int e = blockIdx.x * blockDim.x + threadIdx.x;
    if (e < NE) {
        int d = clampi(ei[NE + e], 0, NN - 1);
        int pos = atomicAdd(&cur[d], 1);
        if (pos >= 0 && pos < NE) csr[pos] = e;
    }
}

// ---------------- fused q|k|v|qe projection: [20000x64] @ [64x1024] via MFMA ----------
// M-tile = 16 (1250 blocks).  Wave w owns cols [w*256,(w+1)*256):
// w=0 -> q (fp32), 1 -> k (into interleaved kv), 2 -> v (into kv), 3 -> qe (bf16).
// MFMA fragment stores are quarter-coalesced (16-lane 64B/32B segments), so outputs
// are staged in PADDED LDS (+4 fp32 / +8 bf16 per row kills the 256-stride 4-way
// bank conflict) and bulk-copied: the 16-node tile is one contiguous span per
// buffer -> perfect dwordx4 streaming stores.
__global__ void __launch_bounds__(256)
gt_qkv_mfma(const float* __restrict__ h, const bf16* __restrict__ Bp,
            const float* __restrict__ bias4,
            float* __restrict__ q, bf16* __restrict__ kv, bf16* __restrict__ qe) {
    int t = threadIdx.x, lane = t & 63, wave = t >> 6;
    int n0 = blockIdx.x * 16;
    int rowA = lane & 15, kg = lane >> 4;

    __shared__ float sQ[16][260];    // 16.6 KB
    __shared__ bf16  sKV[16][520];   // 16.6 KB
    __shared__ bf16  sQE[16][260];   //  8.3 KB

    v8s a[2];
    {
        const float* hr = h + (size_t)(n0 + rowA) * HID;
#pragma unroll
        for (int ks = 0; ks < 2; ++ks) {
            const float* p = hr + ks * 32 + kg * 8;
            float4 x0 = *(const float4*)p;
            float4 x1 = *(const float4*)(p + 4);
            v8s av;
            av[0] = F2BS(x0.x); av[1] = F2BS(x0.y); av[2] = F2BS(x0.z); av[3] = F2BS(x0.w);
            av[4] = F2BS(x1.x); av[5] = F2BS(x1.y); av[6] = F2BS(x1.z); av[7] = F2BS(x1.w);
            a[ks] = av;
        }
    }

    f32x4 acc[16];
#pragma unroll
    for (int nf = 0; nf < 16; ++nf) acc[nf] = (f32x4){0.f, 0.f, 0.f, 0.f};

#pragma unroll
    for (int nf = 0; nf < 16; ++nf) {
        int nfg = wave * 16 + nf;
        v8s b0 = *(const v8s*)(Bp + ((size_t)(nfg * 2 + 0) * 64 + lane) * 8);
        v8s b1 = *(const v8s*)(Bp + ((size_t)(nfg * 2 + 1) * 64 + lane) * 8);
        acc[nf] = __builtin_amdgcn_mfma_f32_16x16x32_bf16(a[0], b0, acc[nf], 0, 0, 0);
        acc[nf] = __builtin_amdgcn_mfma_f32_16x16x32_bf16(a[1], b1, acc[nf], 0, 0, 0);
    }

    int rbase = (lane >> 4) * 4;
#pragma unroll
    for (int nf = 0; nf < 16; ++nf) {
        int cc = nf * 16 + (lane & 15);
        float bias = bias4[wave * 256 + cc];
#pragma unroll
        for (int reg = 0; reg < 4; ++reg) {
            int r = rbase + reg;
            float val = acc[nf][reg] + bias;
            if (wave == 0)      sQ[r][cc] = val;
            else if (wave == 1) sKV[r][((cc >> 2) << 3) + (cc & 3)] = F2B(val);
            else if (wave == 2) sKV[r][((cc >> 2) << 3) + 4 + (cc & 3)] = F2B(val);
            else                sQE[r][cc] = F2B(val);
        }
    }
    __syncthreads();
    // bulk coalesced write-out (tile rows are contiguous in memory)
    float4* qo = (float4*)(q + (size_t)n0 * HC);
    for (int i = t; i < 16 * 64; i += 256) {
        int r = i >> 6, c4 = i & 63;
        qo[i] = *(const float4*)&sQ[r][4 * c4];
    }
    float4* kvo = (float4*)(kv + (size_t)n0 * 512);
    for (int i = t; i < 16 * 64; i += 256) {
        int r = i >> 6, u = i & 63;
        kvo[i] = *(const float4*)&sKV[r][8 * u];
    }
    float4* qeo = (float4*)(qe + (size_t)n0 * HC);
    for (int i = t; i < 16 * 32; i += 256) {
        int r = i >> 5, u = i & 31;
        qeo[i] = *(const float4*)&sQE[r][8 * u];
    }
}

// ---------------- attention core: wave-per-node, kv-interleaved, ping-pong pipeline ----
// lane l owns channels 4l..4l+3.  kv row: unit l = [k0..k3 v0..v3] -> ONE dwordx4
// gather per edge.  A/B pair double-buffer (step 4).  Defer-max softmax (THR=8).
// Outputs: normalized acc_s -> q row (in place), head-mean acc_v -> vm[N][64].
__global__ void gt_attn_core(float* __restrict__ q, const bf16* __restrict__ qe,
                             const bf16* __restrict__ kv, const bf16* __restrict__ ef,
                             const int* __restrict__ rp, const int* __restrict__ csr,
                             const int* __restrict__ ei, float* __restrict__ vm) {
    int t = threadIdx.x;
    int lane = t & 63, wave = t >> 6;
    int n = blockIdx.x * 4 + wave;
    if (n >= NN) return;

    const float4* q4 = (const float4*)q;
    const ushort4* qe4 = (const ushort4*)qe;  // 64 units of 8B per row
    const u16x8* kv8 = (const u16x8*)kv;      // 64 units per row
    const ushort4* e4p = (const ushort4*)ef;
    int elane = lane & 15;

    float4 qv = q4[(size_t)n * 64 + lane];
    ushort4 qeu = qe4[(size_t)n * 64 + lane];
    float4 qev = make_float4(U2F(qeu.x), U2F(qeu.y), U2F(qeu.z), U2F(qeu.w));

    int s0 = clampi(rp[n], 0, NE), s1 = clampi(rp[n + 1], s0, NE);
    float m = -1e30f, lr = 0.f;
    float4 accv = make_float4(0.f, 0.f, 0.f, 0.f);
    float4 accs = make_float4(0.f, 0.f, 0.f, 0.f);

    auto process = [&](u16x8 k0, ushort4 f0, u16x8 k1, ushort4 f1, bool ok0, bool ok1) {
        float p0 = qv.x * U2F(k0[0]) + qv.y * U2F(k0[1]) + qv.z * U2F(k0[2]) + qv.w * U2F(k0[3])
                 + qev.x * U2F(f0.x) + qev.y * U2F(f0.y) + qev.z * U2F(f0.z) + qev.w * U2F(f0.w);
        float p1 = qv.x * U2F(k1[0]) + qv.y * U2F(k1[1]) + qv.z * U2F(k1[2]) + qv.w * U2F(k1[3])
                 + qev.x * U2F(f1.x) + qev.y * U2F(f1.y) + qev.z * U2F(f1.z) + qev.w * U2F(f1.w);
        p0 += __shfl_xor(p0, 8, 16);  p1 += __shfl_xor(p1, 8, 16);
        p0 += __shfl_xor(p0, 4, 16);  p1 += __shfl_xor(p1, 4, 16);
        p0 += __shfl_xor(p0, 2, 16);  p1 += __shfl_xor(p1, 2, 16);
        p0 += __shfl_xor(p0, 1, 16);  p1 += __shfl_xor(p1, 1, 16);
        p0 = ok0 ? p0 * 0.125f : -1e30f;
        p1 = ok1 ? p1 * 0.125f : -1e30f;
        float pm = fmaxf(p0, p1);
        if (__any(pm - m > 8.f)) {
            float nm = fmaxf(m, pm);
            float sc = __expf(m - nm);
            m = nm;
            lr *= sc;
            accv.x *= sc; accv.y *= sc; accv.z *= sc; accv.w *= sc;
            accs.x *= sc; accs.y *= sc; accs.z *= sc; accs.w *= sc;
        }
        float w0 = __expf(p0 - m);
        float w1 = __expf(p1 - m);
        lr += w0 + w1;
        accv.x += w0 * U2F(k0[4]) + w1 * U2F(k1[4]);
        accv.y += w0 * U2F(k0[5]) + w1 * U2F(k1[5]);
        accv.z += w0 * U2F(k0[6]) + w1 * U2F(k1[6]);
        accv.w += w0 * U2F(k0[7]) + w1 * U2F(k1[7]);
        accs.x += w0 * U2F(f0.x) + w1 * U2F(f1.x);
        accs.y += w0 * U2F(f0.y) + w1 * U2F(f1.y);
        accs.z += w0 * U2F(f0.z) + w1 * U2F(f1.z);
        accs.w += w0 * U2F(f0.w) + w1 * U2F(f1.w);
    };

    for (int base = s0; base < s1; base += 64) {
        int cnt = min(64, s1 - base);
        int eL = 0, srcL = 0;
        if (lane < cnt) {
            eL = clampi(csr[base + lane], 0, NE - 1);
            srcL = clampi(ei[eL], 0, NN - 1);
        }
        // preload pair A = edges 0,1 (clamped)
        int jb = min(1, cnt - 1);
        int eA0 = __builtin_amdgcn_readlane(eL, 0), rA0 = __builtin_amdgcn_readlane(srcL, 0);
        int eA1 = __builtin_amdgcn_readlane(eL, jb), rA1 = __builtin_amdgcn_readlane(srcL, jb);
        u16x8 kvA0 = kv8[(size_t)rA0 * 64 + lane];
        u16x8 kvA1 = kv8[(size_t)rA1 * 64 + lane];
        ushort4 efA0 = e4p[(size_t)eA0 * 16 + elane];
        ushort4 efA1 = e4p[(size_t)eA1 * 16 + elane];
        u16x8 kvB0, kvB1;
        ushort4 efB0, efB1;
        for (int i = 0; i < cnt; i += 4) {
            // issue loads for pair B = edges i+2, i+3 (clamped)
            {
                int j2 = min(i + 2, cnt - 1), j3 = min(i + 3, cnt - 1);
                int e2 = __builtin_amdgcn_readlane(eL, j2), r2 = __builtin_amdgcn_readlane(srcL, j2);
                int e3 = __builtin_amdgcn_readlane(eL, j3), r3 = __builtin_amdgcn_readlane(srcL, j3);
                kvB0 = kv8[(size_t)r2 * 64 + lane];
                kvB1 = kv8[(size_t)r3 * 64 + lane];
                efB0 = e4p[(size_t)e2 * 16 + elane];
                efB1 = e4p[(size_t)e3 * 16 + elane];
            }
            process(kvA0, efA0, kvA1, efA1, true, i + 1 < cnt);
            // issue loads for next pair A = edges i+4, i+5 (clamped)
            if (i + 4 < cnt) {
                int j4 = i + 4, j5 = min(i + 5, cnt - 1);
                int e4 = __builtin_amdgcn_readlane(eL, j4), r4 = __builtin_amdgcn_readlane(srcL, j4);
                int e5 = __builtin_amdgcn_readlane(eL, j5), r5 = __builtin_amdgcn_readlane(srcL, j5);
                kvA0 = kv8[(size_t)r4 * 64 + lane];
                kvA1 = kv8[(size_t)r5 * 64 + lane];
                efA0 = e4p[(size_t)e4 * 16 + elane];
                efA1 = e4p[(size_t)e5 * 16 + elane];
            }
            if (i + 2 < cnt) {
                process(kvB0, efB0, kvB1, efB1, true, i + 3 < cnt);
            }
        }
    }
    float inv = (s1 > s0) ? 0.25f / lr : 0.f;   // fold mean-over-heads 0.25
    float4 rs = make_float4(accs.x * inv, accs.y * inv, accs.z * inv, accs.w * inv);
    ((float4*)q)[(size_t)n * 64 + lane] = rs;
    float4 rv = make_float4(accv.x * inv, accv.y * inv, accv.z * inv, accv.w * inv);
    rv.x += __shfl_xor(rv.x, 16, 64); rv.x += __shfl_xor(rv.x, 32, 64);
    rv.y += __shfl_xor(rv.y, 16, 64); rv.y += __shfl_xor(rv.y, 32, 64);
    rv.z += __shfl_xor(rv.z, 16, 64); rv.z += __shfl_xor(rv.z, 32, 64);
    rv.w += __shfl_xor(rv.w, 16, 64); rv.w += __shfl_xor(rv.w, 32, 64);
    if (lane < 16) ((float4*)vm)[(size_t)n * 16 + lane] = rv;
}

// ---------------- epilogue: batched [16 x 320] @ [320 x 64] + vm + res + bskip, LN, ReLU ----------------
// acc_s = q (rows [N][256] = normalized alpha-weighted ef sums)
// acc_vm = vm (dense [N][64] fp32 head-mean of alpha-weighted v)
__global__ void gt_epilogue(const float* __restrict__ acc_s, const float* __restrict__ acc_vm,
                            const float* __restrict__ Wc, const float* __restrict__ bskip,
                            const float* __restrict__ lng, const float* __restrict__ lnb,
                            float* __restrict__ h) {
    int t = threadIdx.x;
    int c = t & 63, qw = t >> 6;
    int n0 = blockIdx.x * EPB;
    __shared__ float sK[EPB][320];   // cols 0..255: acc_s, cols 256..319: res (h)
    __shared__ float sVM[EPB][64];
    const float4* as4 = (const float4*)acc_s;
    for (int i = t; i < EPB * 64; i += 256) {
        int nd = i >> 6, j4 = i & 63;
        *(float4*)&sK[nd][4 * j4] = as4[(size_t)(n0 + nd) * 64 + j4];
    }
    const float4* h4g = (const float4*)h;
    const float4* vm4 = (const float4*)acc_vm;   // 16 float4 per row
    for (int i = t; i < EPB * 16; i += 256) {
        int nd = i >> 4, j4 = i & 15;
        *(float4*)&sK[nd][256 + 4 * j4] = h4g[(size_t)(n0 + nd) * 16 + j4];
        *(float4*)&sVM[nd][4 * j4] = vm4[(size_t)(n0 + nd) * 16 + j4];
    }
    __syncthreads();
    int nb = qw * 4;
    const float4* r0 = (const float4*)&sK[nb][0];
    const float4* r1 = (const float4*)&sK[nb + 1][0];
    const float4* r2 = (const float4*)&sK[nb + 2][0];
    const float4* r3 = (const float4*)&sK[nb + 3][0];
    const float4* W4 = (const float4*)Wc;
    float a0 = 0.f, a1 = 0.f, a2 = 0.f, a3 = 0.f;
#pragma unroll 4
    for (int k4 = 0; k4 < 80; ++k4) {
        float4 w = W4[k4 * 64 + c];
        float4 x0 = r0[k4]; a0 += x0.x * w.x + x0.y * w.y + x0.z * w.z + x0.w * w.w;
        float4 x1 = r1[k4]; a1 += x1.x * w.x + x1.y * w.y + x1.z * w.z + x1.w * w.w;
        float4 x2 = r2[k4]; a2 += x2.x * w.x + x2.y * w.y + x2.z * w.z + x2.w * w.w;
        float4 x3 = r3[k4]; a3 += x3.x * w.x + x3.y * w.y + x3.z * w.z + x3.w * w.w;
    }
    float bsk = bskip[c], g = lng[c], bb = lnb[c];
    float y0 = a0 + sVM[nb][c] + sK[nb][256 + c] + bsk;
    float y1 = a1 + sVM[nb + 1][c] + sK[nb + 1][256 + c] + bsk;
    float y2 = a2 + sVM[nb + 2][c] + sK[nb + 2][256 + c] + bsk;
    float y3 = a3 + sVM[nb + 3][c] + sK[nb + 3][256 + c] + bsk;
    float m0 = y0, m1 = y1, m2 = y2, m3 = y3;
#pragma unroll
    for (int s = 32; s > 0; s >>= 1) {
        m0 += __shfl_xor(m0, s, 64);
        m1 += __shfl_xor(m1, s, 64);
        m2 += __shfl_xor(m2, s, 64);
        m3 += __shfl_xor(m3, s, 64);
    }
    m0 *= (1.f / HID); m1 *= (1.f / HID); m2 *= (1.f / HID); m3 *= (1.f / HID);
    float d0 = y0 - m0, d1 = y1 - m1, d2 = y2 - m2, d3 = y3 - m3;
    float v0 = d0 * d0, v1 = d1 * d1, v2 = d2 * d2, v3 = d3 * d3;
#pragma unroll
    for (int s = 32; s > 0; s >>= 1) {
        v0 += __shfl_xor(v0, s, 64);
        v1 += __shfl_xor(v1, s, 64);
        v2 += __shfl_xor(v2, s, 64);
        v3 += __shfl_xor(v3, s, 64);
    }
    v0 *= (1.f / HID); v1 *= (1.f / HID); v2 *= (1.f / HID); v3 *= (1.f / HID);
    h[(size_t)(n0 + nb) * HID + c]     = fmaxf(d0 * rsqrtf(v0 + 1e-5f) * g + bb, 0.f);
    h[(size_t)(n0 + nb + 1) * HID + c] = fmaxf(d1 * rsqrtf(v1 + 1e-5f) * g + bb, 0.f);
    h[(size_t)(n0 + nb + 2) * HID + c] = fmaxf(d2 * rsqrtf(v2 + 1e-5f) * g + bb, 0.f);
    h[(size_t)(n0 + nb + 3) * HID + c] = fmaxf(d3 * rsqrtf(v3 + 1e-5f) * g + bb, 0.f);
}

// ---------------- pool stage 1: segment partial sums + atomics (batch sorted) ----------------
__global__ void gt_pool_sum(const float* __restrict__ h, const int* __restrict__ batch,
                            float* __restrict__ psum) {
    int t = threadIdx.x;
    int c = t & 63, slot = t >> 6;
    int n0 = blockIdx.x * 256;
    float acc = 0.f;
    int curg = -1;
    for (int i = slot; i < 256; i += 4) {
        int n = n0 + i;
        if (n >= NN) break;
        int g = clampi(batch[n], 0, NGRAPHS - 1);
        float val = h[(size_t)n * HID + c];
        if (g != curg) {
            if (curg >= 0) atomicAdd(&psum[curg * HID + c], acc);
            curg = g;
            acc = 0.f;
        }
        acc += val;
    }
    if (curg >= 0) atomicAdd(&psum[curg * HID + c], acc);
}

// ---------------- pool stage 2: divide by true count + classifier ----------------
__global__ void gt_classify(const float* __restrict__ psum, const int* __restrict__ batch,
                            const float* __restrict__ W, const float* __restrict__ b,
                            float* __restrict__ out) {
    int g = blockIdx.x;
    int c = threadIdx.x;
    __shared__ float pooled[HID];
    __shared__ float lg[4];
    __shared__ int bounds[2];
    if (c < 2) {
        int target = g + c;
        int lo = 0, hi = NN;
        while (lo < hi) {
            int mid = (lo + hi) >> 1;
            if (batch[mid] < target) lo = mid + 1; else hi = mid;
        }
        bounds[c] = lo;
    }
    __syncthreads();
    float divf = fmaxf((float)(bounds[1] - bounds[0]), 1.f);
    pooled[c] = psum[g * HID + c] / divf;
    __syncthreads();
    if (c < NCLASSES) {
        float acc = 0.f;
        for (int j = 0; j < HID; ++j) acc += pooled[j] * W[j * NCLASSES + c];
        lg[c] = acc + b[c];
    }
    __syncthreads();
    if (c == 0) {
        float m = fmaxf(lg[0], fmaxf(lg[1], lg[2]));
        float ssum = 0.f;
        for (int cc = 0; cc < NCLASSES; ++cc) ssum += __expf(lg[cc] - m);
        float lse = logf(ssum);
        for (int cc = 0; cc < NCLASSES; ++cc) out[g * NCLASSES + cc] = lg[cc] - m - lse;
    }
}

extern "C" void kernel_launch(void* const* d_in, const int* in_sizes, int n_in,
                              void* d_out, int out_size, void* d_ws, size_t ws_size,
                              hipStream_t stream) {
    float* out = (float*)d_out;

    static const int EXPECT[23] = {2560000, 2048000, 8192, 64, 512, 64, 4096, 64,
                                   49152, 768, 49152, 768, 49152, 768, 49152,
                                   12288, 192, 192, 192, 192, 3, 512000, 20000};
    int bad = -1;
    if (n_in != 23) bad = 99;
    else {
        for (int i = 0; i < 23; ++i) {
            if (in_sizes[i] != EXPECT[i]) { bad = i; break; }
        }
    }
    if (bad >= 0) {
        float val = (bad == 99) ? 4000.f : (5000.f + 10.f * bad);
        gt_write_const<<<1, 256, 0, stream>>>(out, out_size, val);
        return;
    }

    const float* x        = (const float*)d_in[0];
    const float* edge_attr= (const float*)d_in[1];
    const float* node_W   = (const float*)d_in[2];
    const float* node_b   = (const float*)d_in[3];
    const float* e1_W     = (const float*)d_in[4];
    const float* e1_b     = (const float*)d_in[5];
    const float* e2_W     = (const float*)d_in[6];
    const float* e2_b     = (const float*)d_in[7];
    const float* Wq       = (const float*)d_in[8];
    const float* bq       = (const float*)d_in[9];
    const float* Wk       = (const float*)d_in[10];
    const float* bk       = (const float*)d_in[11];
    const float* Wv       = (const float*)d_in[12];
    const float* bv       = (const float*)d_in[13];
    const float* We       = (const float*)d_in[14];
    const float* Wskip    = (const float*)d_in[15];
    const float* bskip    = (const float*)d_in[16];
    const float* lng      = (const float*)d_in[17];
    const float* lnb      = (const float*)d_in[18];
    const float* cls_W    = (const float*)d_in[19];
    const float* cls_b    = (const float*)d_in[20];
    const int*   ei       = (const int*)d_in[21];
    const int*   batch    = (const int*)d_in[22];

    char* w = (char*)d_ws;
    auto alloc = [&](size_t bytes) -> char* {
        char* p = w;
        w += (bytes + 255) & ~(size_t)255;
        return p;
    };
    float* h     = (float*)alloc((size_t)NN * HID * 4);
    bf16*  ef    = (bf16*)alloc((size_t)NE * HID * 2);
    float* q     = (float*)alloc((size_t)NN * HC * 4);
    bf16*  kv    = (bf16*)alloc((size_t)NN * 512 * 2);
    bf16*  qe    = (bf16*)alloc((size_t)NN * HC * 2);
    float* vm    = (float*)alloc((size_t)NN * HID * 4);
    float* Wqe   = (float*)alloc((size_t)NLAYERS * HID * HC * 4);
    float* bias4 = (float*)alloc((size_t)NLAYERS * 1024 * 4);
    bf16*  Bp    = (bf16*)alloc((size_t)NLAYERS * 8192 * 8 * 2);
    bf16*  B2p   = (bf16*)alloc((size_t)512 * 8 * 2);
    float* Wc    = (float*)alloc((size_t)NLAYERS * 320 * 64 * 4);
    float* psum  = (float*)alloc((size_t)NGRAPHS * HID * 4);
    int*   cnt   = (int*)alloc((size_t)NN * 4);
    int*   rp    = (int*)alloc((size_t)(NN + 1) * 4);
    int*   cur   = (int*)alloc((size_t)NN * 4);
    int*   csr   = (int*)alloc((size_t)NE * 4);

    gt_node_proj<<<(NN + 3) / 4, 256, 0, stream>>>(x, node_W, node_b, h);
    gt_prep_wqe<<<NLAYERS * 65, 256, 0, stream>>>(Wq, bq, bk, bv, We, Wqe, bias4);
    gt_pack_qkv<<<(NLAYERS * 8192 + 255) / 256, 256, 0, stream>>>(Wq, Wk, Wv, Wqe, Bp);
    gt_pack_w2<<<2, 256, 0, stream>>>(e2_W, B2p);
    gt_edge_mlp<<<NE / EB, 256, 0, stream>>>(edge_attr, e1_W, e1_b, B2p, e2_b, ef);
    gt_prep_wcomb<<<(NLAYERS * 320 * 64 + 255) / 256, 256, 0, stream>>>(We, Wskip, Wc);
    gt_zero_i32<<<(NN + 255) / 256, 256, 0, stream>>>(cnt, NN);
    gt_count_dst<<<(NE + 255) / 256, 256, 0, stream>>>(ei, cnt);
    gt_scan_csr<<<1, 256, 0, stream>>>(cnt, rp, cur);
    gt_fill_csr<<<(NE + 255) / 256, 256, 0, stream>>>(ei, cur, csr);

    for (int l = 0; l < NLAYERS; ++l) {
        const bf16* Bp_l  = Bp + (size_t)l * 8192 * 8;
        const float* b4_l = bias4 + (size_t)l * 1024;
        const float* Wc_l = Wc + (size_t)l * 320 * 64;
        const float* bs_l = bskip + (size_t)l * HID;
        const float* lg_l = lng + (size_t)l * HID;
        const float* lb_l = lnb + (size_t)l * HID;

        gt_qkv_mfma<<<NN / 16, 256, 0, stream>>>(h, Bp_l, b4_l, q, kv, qe);
        gt_attn_core<<<(NN + 3) / 4, 256, 0, stream>>>(q, qe, kv, ef, rp, csr, ei, vm);
        gt_epilogue<<<NN / EPB, 256, 0, stream>>>(q, vm, Wc_l, bs_l, lg_l, lb_l, h);
    }

    gt_zero_i32<<<(NGRAPHS * HID + 255) / 256, 256, 0, stream>>>((int*)psum, NGRAPHS * HID);
    gt_pool_sum<<<(NN + 255) / 256, 256, 0, stream>>>(h, batch, psum);
    gt_classify<<<NGRAPHS, HID, 0, stream>>>(psum, batch, cls_W, cls_b, out);
}

// Round 13
// 547.211 us; speedup vs baseline: 1.2511x; 1.0823x over previous
//
#include <hip/hip_runtime.h>
#include <hip/hip_bf16.h>
#include <math.h>

#define NN 20000
#define NE 256000
#define NODE_DIM_ 128
#define EDGE_DIM_ 8
#define HID 64
#define HEADS 4
#define NLAYERS 3
#define NCLASSES 3
#define NGRAPHS 64
#define HC 256  // HEADS*HID
#define EB 64   // edges per block in edge_mlp
#define EPB 16  // nodes per block in epilogue

typedef __hip_bfloat16 bf16;
using v8s = __attribute__((ext_vector_type(8))) short;
using u16x8 = __attribute__((ext_vector_type(8))) unsigned short;
using f32x4 = __attribute__((ext_vector_type(4))) float;

__device__ __forceinline__ float B2F(bf16 x) { return __bfloat162float(x); }
__device__ __forceinline__ bf16 F2B(float x) { return __float2bfloat16(x); }
__device__ __forceinline__ short F2BS(float x) {
    union { bf16 b; short s; } u; u.b = __float2bfloat16(x); return u.s;
}
__device__ __forceinline__ float U2F(unsigned short u) { return __uint_as_float(((unsigned)u) << 16); }
__device__ __forceinline__ int clampi(int x, int lo, int hi) { return min(max(x, lo), hi); }

// ---------------- diagnostics ----------------
__global__ void gt_write_const(float* out, int n, float val) {
    int i = blockIdx.x * blockDim.x + threadIdx.x;
    if (i < n) out[i] = val;
}

// ---------------- utility ----------------
__global__ void gt_zero_i32(int* p, int n) {
    int i = blockIdx.x * blockDim.x + threadIdx.x;
    if (i < n) p[i] = 0;
}

// ---------------- Wqe = Wq-head @ We-head (fused qe weight) + bias4 ----------------
__global__ void gt_prep_wqe(const float* __restrict__ Wq, const float* __restrict__ bq,
                            const float* __restrict__ bk, const float* __restrict__ bv,
                            const float* __restrict__ We,
                            float* __restrict__ Wqe, float* __restrict__ bias4) {
    int b = blockIdx.x;
    int l = b / 65, kk = b % 65;
    int t = threadIdx.x;
    int hh = t >> 6, d = t & 63;
    const float* Weh = We + (size_t)l * HID * HC + (size_t)d * HC + hh * 64;
    if (kk < 64) {
        const float* Wqr = Wq + (size_t)l * HID * HC + (size_t)kk * HC + hh * 64;
        float s = 0.f;
        for (int c = 0; c < 64; ++c) s += Wqr[c] * Weh[c];
        Wqe[(size_t)l * HID * HC + (size_t)kk * HC + t] = s;
    } else {
        const float* bqr = bq + (size_t)l * HC + hh * 64;
        float s = 0.f;
        for (int c = 0; c < 64; ++c) s += bqr[c] * Weh[c];
        bias4[(size_t)l * 1024 + 768 + t] = s;
        bias4[(size_t)l * 1024 + t]       = bq[(size_t)l * HC + t];
        bias4[(size_t)l * 1024 + 256 + t] = bk[(size_t)l * HC + t];
        bias4[(size_t)l * 1024 + 512 + t] = bv[(size_t)l * HC + t];
    }
}

// ---------------- pack W4 = [Wq|Wk|Wv|Wqe] (64 x 1024) into per-fragment bf16 layout ----
__global__ void gt_pack_qkv(const float* __restrict__ Wq, const float* __restrict__ Wk,
                            const float* __restrict__ Wv, const float* __restrict__ Wqe,
                            bf16* __restrict__ Bp) {
    int idx = blockIdx.x * 256 + threadIdx.x;
    if (idx >= NLAYERS * 8192) return;
    int lane = idx & 63;
    int ks = (idx >> 6) & 1;
    int nf = (idx >> 7) & 63;
    int l = idx >> 13;
    int col = nf * 16 + (lane & 15);
    int k0 = ks * 32 + (lane >> 4) * 8;
    const float* src;
    int c;
    if (col < 256)      { src = Wq  + (size_t)l * HID * HC; c = col; }
    else if (col < 512) { src = Wk  + (size_t)l * HID * HC; c = col - 256; }
    else if (col < 768) { src = Wv  + (size_t)l * HID * HC; c = col - 512; }
    else                { src = Wqe + (size_t)l * HID * HC; c = col - 768; }
    bf16* dst = Bp + (size_t)idx * 8;
#pragma unroll
    for (int j = 0; j < 8; ++j) dst[j] = F2B(src[(size_t)(k0 + j) * HC + c]);
}

// ---------------- pack W2 (64x64) into fragment layout ----------------
__global__ void gt_pack_w2(const float* __restrict__ W2, bf16* __restrict__ B2p) {
    int idx = blockIdx.x * 256 + threadIdx.x;
    if (idx >= 512) return;
    int lane = idx & 63;
    int ks = (idx >> 6) & 1;
    int nf = idx >> 7;   // 0..3
    int col = nf * 16 + (lane & 15);
    int k0 = ks * 32 + (lane >> 4) * 8;
    bf16* dst = B2p + (size_t)idx * 8;
#pragma unroll
    for (int j = 0; j < 8; ++j) dst[j] = F2B(W2[(size_t)(k0 + j) * HID + col]);
}

// Wcomb for the epilogue GEMM: rows 0..255 = We2[u][c] = We[j][h*64+c] (u=h*64+j),
// rows 256..319 = Wskip[j][c].  Packed as [80][64] float4: Wc[l][(k>>2)*64+c][k&3].
__global__ void gt_prep_wcomb(const float* __restrict__ We, const float* __restrict__ Wskip,
                              float* __restrict__ Wc) {
    int idx = blockIdx.x * blockDim.x + threadIdx.x;
    if (idx >= NLAYERS * 320 * 64) return;
    int l = idx / (320 * 64);
    int r = idx % (320 * 64);
    int kk = r / 64;
    int c = r % 64;
    float val;
    if (kk < 256) {
        int hh = kk >> 6, j = kk & 63;
        val = We[(size_t)l * HID * HC + (size_t)j * HC + hh * 64 + c];
    } else {
        int j = kk - 256;
        val = Wskip[(size_t)l * HID * HID + (size_t)j * HID + c];
    }
    Wc[(size_t)l * 320 * 64 + (size_t)((kk >> 2) * 64 + c) * 4 + (kk & 3)] = val;
}

// ---------------- h = x @ node_W + node_b  (4 nodes/block) ----------------
__global__ void gt_node_proj(const float* __restrict__ x, const float* __restrict__ W,
                             const float* __restrict__ b, float* __restrict__ h) {
    int t = threadIdx.x;
    int n = blockIdx.x * 4 + (t >> 6);
    int c = t & 63;
    __shared__ float xr[4][NODE_DIM_];
    for (int i = t; i < 4 * NODE_DIM_; i += 256) {
        int nn = blockIdx.x * 4 + i / NODE_DIM_;
        xr[i / NODE_DIM_][i % NODE_DIM_] = (nn < NN) ? x[(size_t)nn * NODE_DIM_ + i % NODE_DIM_] : 0.f;
    }
    __syncthreads();
    if (n >= NN) return;
    float acc = 0.f;
#pragma unroll 8
    for (int j = 0; j < NODE_DIM_; ++j) acc += xr[t >> 6][j] * W[j * HID + c];
    h[(size_t)n * HID + c] = acc + b[c];
}

// ---------------- edge MLP: layer1 VALU (K=8) -> bf16 LDS, layer2 MFMA ----------------
__global__ void gt_edge_mlp(const float* __restrict__ ea, const float* __restrict__ W1,
                            const float* __restrict__ b1, const bf16* __restrict__ B2p,
                            const float* __restrict__ b2, bf16* __restrict__ ef) {
    int t = threadIdx.x;
    int c = t & 63, slot = t >> 6;
    int e0 = blockIdx.x * EB;
    __shared__ float aS[EB][EDGE_DIM_];
    __shared__ bf16 t1s[EB * 64];   // XOR-swizzled 16B units: unit u of row r at u^(r&7)
    for (int i = t; i < EB * EDGE_DIM_; i += 256) {
        ((float*)aS)[i] = ea[(size_t)e0 * EDGE_DIM_ + i];
    }
    float w1r[EDGE_DIM_];
#pragma unroll
    for (int j = 0; j < EDGE_DIM_; ++j) w1r[j] = W1[j * HID + c];
    float b1c = b1[c];
    __syncthreads();
    int cu = c >> 3, ci = c & 7;
#pragma unroll
    for (int es16 = 0; es16 < 16; ++es16) {
        int es = slot * 16 + es16;
        float acc = b1c;
#pragma unroll
        for (int j = 0; j < EDGE_DIM_; ++j) acc += aS[es][j] * w1r[j];
        int cs = ((cu ^ (es & 7)) << 3) | ci;
        t1s[es * 64 + cs] = F2B(fmaxf(acc, 0.f));
    }
    __syncthreads();
    int lane = t & 63, wave = slot;
    v8s bfr0 = *(const v8s*)(B2p + ((size_t)(wave * 2 + 0) * 64 + lane) * 8);
    v8s bfr1 = *(const v8s*)(B2p + ((size_t)(wave * 2 + 1) * 64 + lane) * 8);
    int rowA = lane & 15, kg = lane >> 4;
    f32x4 acc[4];
#pragma unroll
    for (int mf = 0; mf < 4; ++mf) acc[mf] = (f32x4){0.f, 0.f, 0.f, 0.f};
#pragma unroll
    for (int mf = 0; mf < 4; ++mf) {
        int r = mf * 16 + rowA;
        int u0 = 0 * 4 + kg, u1 = 1 * 4 + kg;
        v8s a0 = *(const v8s*)&t1s[r * 64 + ((u0 ^ (r & 7)) << 3)];
        v8s a1 = *(const v8s*)&t1s[r * 64 + ((u1 ^ (r & 7)) << 3)];
        acc[mf] = __builtin_amdgcn_mfma_f32_16x16x32_bf16(a0, bfr0, acc[mf], 0, 0, 0);
        acc[mf] = __builtin_amdgcn_mfma_f32_16x16x32_bf16(a1, bfr1, acc[mf], 0, 0, 0);
    }
    int col = wave * 16 + (lane & 15);
    float bb = b2[col];
    int rbase = (lane >> 4) * 4;
#pragma unroll
    for (int mf = 0; mf < 4; ++mf) {
#pragma unroll
        for (int reg = 0; reg < 4; ++reg) {
            int e = e0 + mf * 16 + rbase + reg;
            ef[(size_t)e * HID + col] = F2B(acc[mf][reg] + bb);
        }
    }
}

// ---------------- CSR build over dst ----------------
__global__ void gt_count_dst(const int* __restrict__ ei, int* cnt) {
    int e = blockIdx.x * blockDim.x + threadIdx.x;
    if (e < NE) {
        int d = clampi(ei[NE + e], 0, NN - 1);
        atomicAdd(&cnt[d], 1);
    }
}

__global__ void gt_scan_csr(const int* __restrict__ cnt, int* __restrict__ rp, int* __restrict__ cur) {
    __shared__ int part[256];
    int tid = threadIdx.x;
    const int CH = (NN + 255) / 256;
    int s0 = tid * CH, s1 = min(s0 + CH, NN);
    int s = 0;
    for (int i = s0; i < s1; ++i) s += cnt[i];
    part[tid] = s;
    __syncthreads();
    for (int off = 1; off < 256; off <<= 1) {
        int vv = (tid >= off) ? part[tid - off] : 0;
        __syncthreads();
        if (tid >= off) part[tid] += vv;
        __syncthreads();
    }
    int base = (tid == 0) ? 0 : part[tid - 1];
    for (int i = s0; i < s1; ++i) {
        rp[i] = base;
        cur[i] = base;
        base += cnt[i];
    }
    if (tid == 255) rp[NN] = part[255];
}

__global__ void gt_fill_csr(const int* __restrict__ ei, int* cur, int* csr) {
    int e = blockIdx.x * blockDim.x + threadIdx.x;
    if (e < NE) {
        int d = clampi(ei[NE + e], 0, NN - 1);
        int pos = atomicAdd(&cur[d], 1);
        if (pos >= 0 && pos < NE) csr[pos] = e;
    }
}

// ---------------- fused q|k|v|qe projection: [20000x64] @ [64x1024] via MFMA ----------
// M-tile = 16 (1250 blocks).  Wave w owns cols [w*256,(w+1)*256):
// w=0 -> q (fp32), 1 -> k (into interleaved kv), 2 -> v (into kv), 3 -> qe (bf16).
// TRANSPOSED OPERANDS: D = Wfrag(A) x hfrag(B) so D col = node, D row = channel.
// Each acc[mf] then holds 4 CONSECUTIVE channels of ONE node -> float4/short4
// stores (16 stores/thread of 8-16B vs 64 stores of 2-4B).  Fragment layouts of
// A and B for 16x16x32 are symmetric (lane&15 = M/N idx, lane>>4 = k-group), so
// loads and packing are unchanged; output values bit-identical.
__global__ void __launch_bounds__(256)
gt_qkv_mfma(const float* __restrict__ h, const bf16* __restrict__ Bp,
            const float* __restrict__ bias4,
            float* __restrict__ q, bf16* __restrict__ kv, bf16* __restrict__ qe) {
    int t = threadIdx.x, lane = t & 63, wave = t >> 6;
    int n0 = blockIdx.x * 16;
    int rowA = lane & 15, kg = lane >> 4;

    // h fragment (B operand): node = n0+rowA, k = ks*32 + kg*8 + j
    v8s a[2];
    {
        const float* hr = h + (size_t)(n0 + rowA) * HID;
#pragma unroll
        for (int ks = 0; ks < 2; ++ks) {
            const float* p = hr + ks * 32 + kg * 8;
            float4 x0 = *(const float4*)p;
            float4 x1 = *(const float4*)(p + 4);
            v8s av;
            av[0] = F2BS(x0.x); av[1] = F2BS(x0.y); av[2] = F2BS(x0.z); av[3] = F2BS(x0.w);
            av[4] = F2BS(x1.x); av[5] = F2BS(x1.y); av[6] = F2BS(x1.z); av[7] = F2BS(x1.w);
            a[ks] = av;
        }
    }

    f32x4 acc[16];
#pragma unroll
    for (int mf = 0; mf < 16; ++mf) acc[mf] = (f32x4){0.f, 0.f, 0.f, 0.f};

#pragma unroll
    for (int mf = 0; mf < 16; ++mf) {
        int nfg = wave * 16 + mf;
        v8s b0 = *(const v8s*)(Bp + ((size_t)(nfg * 2 + 0) * 64 + lane) * 8);
        v8s b1 = *(const v8s*)(Bp + ((size_t)(nfg * 2 + 1) * 64 + lane) * 8);
        acc[mf] = __builtin_amdgcn_mfma_f32_16x16x32_bf16(b0, a[0], acc[mf], 0, 0, 0);
        acc[mf] = __builtin_amdgcn_mfma_f32_16x16x32_bf16(b1, a[1], acc[mf], 0, 0, 0);
    }

    int node = n0 + rowA;
    int rrow = kg * 4;          // channel base within 16-wide tile
#pragma unroll
    for (int mf = 0; mf < 16; ++mf) {
        int cc = mf * 16 + rrow;                 // channel within wave's 256-block
        float4 bi = *(const float4*)&bias4[wave * 256 + cc];
        float v0 = acc[mf][0] + bi.x;
        float v1 = acc[mf][1] + bi.y;
        float v2 = acc[mf][2] + bi.z;
        float v3 = acc[mf][3] + bi.w;
        if (wave == 0) {
            *(float4*)&q[(size_t)node * HC + cc] = make_float4(v0, v1, v2, v3);
        } else if (wave == 1) {
            short4 s;
            s.x = F2BS(v0); s.y = F2BS(v1); s.z = F2BS(v2); s.w = F2BS(v3);
            *(short4*)&kv[(size_t)node * 512 + (cc >> 2) * 8] = s;
        } else if (wave == 2) {
            short4 s;
            s.x = F2BS(v0); s.y = F2BS(v1); s.z = F2BS(v2); s.w = F2BS(v3);
            *(short4*)&kv[(size_t)node * 512 + (cc >> 2) * 8 + 4] = s;
        } else {
            short4 s;
            s.x = F2BS(v0); s.y = F2BS(v1); s.z = F2BS(v2); s.w = F2BS(v3);
            *(short4*)&qe[(size_t)node * HC + cc] = s;
        }
    }
}

// ---------------- attention core: wave-per-node, kv-interleaved, ping-pong pipeline ----
// lane l owns channels 4l..4l+3.  kv row: unit l = [k0..k3 v0..v3] -> ONE dwordx4
// gather per edge.  A/B pair double-buffer (step 4).  Defer-max softmax (THR=8).
// Outputs: normalized acc_s -> q row (in place), head-mean acc_v -> vm[N][64].
__global__ void gt_attn_core(float* __restrict__ q, const bf16* __restrict__ qe,
                             const bf16* __restrict__ kv, const bf16* __restrict__ ef,
                             const int* __restrict__ rp, const int* __restrict__ csr,
                             const int* __restrict__ ei, float* __restrict__ vm) {
    int t = threadIdx.x;
    int lane = t & 63, wave = t >> 6;
    int n = blockIdx.x * 4 + wave;
    if (n >= NN) return;

    const float4* q4 = (const float4*)q;
    const ushort4* qe4 = (const ushort4*)qe;  // 64 units of 8B per row
    const u16x8* kv8 = (const u16x8*)kv;      // 64 units per row
    const ushort4* e4p = (const ushort4*)ef;
    int elane = lane & 15;

    float4 qv = q4[(size_t)n * 64 + lane];
    ushort4 qeu = qe4[(size_t)n * 64 + lane];
    float4 qev = make_float4(U2F(qeu.x), U2F(qeu.y), U2F(qeu.z), U2F(qeu.w));

    int s0 = clampi(rp[n], 0, NE), s1 = clampi(rp[n + 1], s0, NE);
    float m = -1e30f, lr = 0.f;
    float4 accv = make_float4(0.f, 0.f, 0.f, 0.f);
    float4 accs = make_float4(0.f, 0.f, 0.f, 0.f);

    auto process = [&](u16x8 k0, ushort4 f0, u16x8 k1, ushort4 f1, bool ok0, bool ok1) {
        float p0 = qv.x * U2F(k0[0]) + qv.y * U2F(k0[1]) + qv.z * U2F(k0[2]) + qv.w * U2F(k0[3])
                 + qev.x * U2F(f0.x) + qev.y * U2F(f0.y) + qev.z * U2F(f0.z) + qev.w * U2F(f0.w);
        float p1 = qv.x * U2F(k1[0]) + qv.y * U2F(k1[1]) + qv.z * U2F(k1[2]) + qv.w * U2F(k1[3])
                 + qev.x * U2F(f1.x) + qev.y * U2F(f1.y) + qev.z * U2F(f1.z) + qev.w * U2F(f1.w);
        p0 += __shfl_xor(p0, 8, 16);  p1 += __shfl_xor(p1, 8, 16);
        p0 += __shfl_xor(p0, 4, 16);  p1 += __shfl_xor(p1, 4, 16);
        p0 += __shfl_xor(p0, 2, 16);  p1 += __shfl_xor(p1, 2, 16);
        p0 += __shfl_xor(p0, 1, 16);  p1 += __shfl_xor(p1, 1, 16);
        p0 = ok0 ? p0 * 0.125f : -1e30f;
        p1 = ok1 ? p1 * 0.125f : -1e30f;
        float pm = fmaxf(p0, p1);
        if (__any(pm - m > 8.f)) {
            float nm = fmaxf(m, pm);
            float sc = __expf(m - nm);
            m = nm;
            lr *= sc;
            accv.x *= sc; accv.y *= sc; accv.z *= sc; accv.w *= sc;
            accs.x *= sc; accs.y *= sc; accs.z *= sc; accs.w *= sc;
        }
        float w0 = __expf(p0 - m);
        float w1 = __expf(p1 - m);
        lr += w0 + w1;
        accv.x += w0 * U2F(k0[4]) + w1 * U2F(k1[4]);
        accv.y += w0 * U2F(k0[5]) + w1 * U2F(k1[5]);
        accv.z += w0 * U2F(k0[6]) + w1 * U2F(k1[6]);
        accv.w += w0 * U2F(k0[7]) + w1 * U2F(k1[7]);
        accs.x += w0 * U2F(f0.x) + w1 * U2F(f1.x);
        accs.y += w0 * U2F(f0.y) + w1 * U2F(f1.y);
        accs.z += w0 * U2F(f0.z) + w1 * U2F(f1.z);
        accs.w += w0 * U2F(f0.w) + w1 * U2F(f1.w);
    };

    for (int base = s0; base < s1; base += 64) {
        int cnt = min(64, s1 - base);
        int eL = 0, srcL = 0;
        if (lane < cnt) {
            eL = clampi(csr[base + lane], 0, NE - 1);
            srcL = clampi(ei[eL], 0, NN - 1);
        }
        // preload pair A = edges 0,1 (clamped)
        int jb = min(1, cnt - 1);
        int eA0 = __builtin_amdgcn_readlane(eL, 0), rA0 = __builtin_amdgcn_readlane(srcL, 0);
        int eA1 = __builtin_amdgcn_readlane(eL, jb), rA1 = __builtin_amdgcn_readlane(srcL, jb);
        u16x8 kvA0 = kv8[(size_t)rA0 * 64 + lane];
        u16x8 kvA1 = kv8[(size_t)rA1 * 64 + lane];
        ushort4 efA0 = e4p[(size_t)eA0 * 16 + elane];
        ushort4 efA1 = e4p[(size_t)eA1 * 16 + elane];
        u16x8 kvB0, kvB1;
        ushort4 efB0, efB1;
        for (int i = 0; i < cnt; i += 4) {
            // issue loads for pair B = edges i+2, i+3 (clamped)
            {
                int j2 = min(i + 2, cnt - 1), j3 = min(i + 3, cnt - 1);
                int e2 = __builtin_amdgcn_readlane(eL, j2), r2 = __builtin_amdgcn_readlane(srcL, j2);
                int e3 = __builtin_amdgcn_readlane(eL, j3), r3 = __builtin_amdgcn_readlane(srcL, j3);
                kvB0 = kv8[(size_t)r2 * 64 + lane];
                kvB1 = kv8[(size_t)r3 * 64 + lane];
                efB0 = e4p[(size_t)e2 * 16 + elane];
                efB1 = e4p[(size_t)e3 * 16 + elane];
            }
            process(kvA0, efA0, kvA1, efA1, true, i + 1 < cnt);
            // issue loads for next pair A = edges i+4, i+5 (clamped)
            if (i + 4 < cnt) {
                int j4 = i + 4, j5 = min(i + 5, cnt - 1);
                int e4 = __builtin_amdgcn_readlane(eL, j4), r4 = __builtin_amdgcn_readlane(srcL, j4);
                int e5 = __builtin_amdgcn_readlane(eL, j5), r5 = __builtin_amdgcn_readlane(srcL, j5);
                kvA0 = kv8[(size_t)r4 * 64 + lane];
                kvA1 = kv8[(size_t)r5 * 64 + lane];
                efA0 = e4p[(size_t)e4 * 16 + elane];
                efA1 = e4p[(size_t)e5 * 16 + elane];
            }
            if (i + 2 < cnt) {
                process(kvB0, efB0, kvB1, efB1, true, i + 3 < cnt);
            }
        }
    }
    float inv = (s1 > s0) ? 0.25f / lr : 0.f;   // fold mean-over-heads 0.25
    float4 rs = make_float4(accs.x * inv, accs.y * inv, accs.z * inv, accs.w * inv);
    ((float4*)q)[(size_t)n * 64 + lane] = rs;
    float4 rv = make_float4(accv.x * inv, accv.y * inv, accv.z * inv, accv.w * inv);
    rv.x += __shfl_xor(rv.x, 16, 64); rv.x += __shfl_xor(rv.x, 32, 64);
    rv.y += __shfl_xor(rv.y, 16, 64); rv.y += __shfl_xor(rv.y, 32, 64);
    rv.z += __shfl_xor(rv.z, 16, 64); rv.z += __shfl_xor(rv.z, 32, 64);
    rv.w += __shfl_xor(rv.w, 16, 64); rv.w += __shfl_xor(rv.w, 32, 64);
    if (lane < 16) ((float4*)vm)[(size_t)n * 16 + lane] = rv;
}

// ---------------- epilogue: batched [16 x 320] @ [320 x 64] + vm + res + bskip, LN, ReLU ----------------
// acc_s = q (rows [N][256] = normalized alpha-weighted ef sums)
// acc_vm = vm (dense [N][64] fp32 head-mean of alpha-weighted v)
__global__ void gt_epilogue(const float* __restrict__ acc_s, const float* __restrict__ acc_vm,
                            const float* __restrict__ Wc, const float* __restrict__ bskip,
                            const float* __restrict__ lng, const float* __restrict__ lnb,
                            float* __restrict__ h) {
    int t = threadIdx.x;
    int c = t & 63, qw = t >> 6;
    int n0 = blockIdx.x * EPB;
    __shared__ float sK[EPB][320];   // cols 0..255: acc_s, cols 256..319: res (h)
    __shared__ float sVM[EPB][64];
    const float4* as4 = (const float4*)acc_s;
    for (int i = t; i < EPB * 64; i += 256) {
        int nd = i >> 6, j4 = i & 63;
        *(float4*)&sK[nd][4 * j4] = as4[(size_t)(n0 + nd) * 64 + j4];
    }
    const float4* h4g = (const float4*)h;
    const float4* vm4 = (const float4*)acc_vm;   // 16 float4 per row
    for (int i = t; i < EPB * 16; i += 256) {
        int nd = i >> 4, j4 = i & 15;
        *(float4*)&sK[nd][256 + 4 * j4] = h4g[(size_t)(n0 + nd) * 16 + j4];
        *(float4*)&sVM[nd][4 * j4] = vm4[(size_t)(n0 + nd) * 16 + j4];
    }
    __syncthreads();
    int nb = qw * 4;
    const float4* r0 = (const float4*)&sK[nb][0];
    const float4* r1 = (const float4*)&sK[nb + 1][0];
    const float4* r2 = (const float4*)&sK[nb + 2][0];
    const float4* r3 = (const float4*)&sK[nb + 3][0];
    const float4* W4 = (const float4*)Wc;
    float a0 = 0.f, a1 = 0.f, a2 = 0.f, a3 = 0.f;
#pragma unroll 4
    for (int k4 = 0; k4 < 80; ++k4) {
        float4 w = W4[k4 * 64 + c];
        float4 x0 = r0[k4]; a0 += x0.x * w.x + x0.y * w.y + x0.z * w.z + x0.w * w.w;
        float4 x1 = r1[k4]; a1 += x1.x * w.x + x1.y * w.y + x1.z * w.z + x1.w * w.w;
        float4 x2 = r2[k4]; a2 += x2.x * w.x + x2.y * w.y + x2.z * w.z + x2.w * w.w;
        float4 x3 = r3[k4]; a3 += x3.x * w.x + x3.y * w.y + x3.z * w.z + x3.w * w.w;
    }
    float bsk = bskip[c], g = lng[c], bb = lnb[c];
    float y0 = a0 + sVM[nb][c] + sK[nb][256 + c] + bsk;
    float y1 = a1 + sVM[nb + 1][c] + sK[nb + 1][256 + c] + bsk;
    float y2 = a2 + sVM[nb + 2][c] + sK[nb + 2][256 + c] + bsk;
    float y3 = a3 + sVM[nb + 3][c] + sK[nb + 3][256 + c] + bsk;
    float m0 = y0, m1 = y1, m2 = y2, m3 = y3;
#pragma unroll
    for (int s = 32; s > 0; s >>= 1) {
        m0 += __shfl_xor(m0, s, 64);
        m1 += __shfl_xor(m1, s, 64);
        m2 += __shfl_xor(m2, s, 64);
        m3 += __shfl_xor(m3, s, 64);
    }
    m0 *= (1.f / HID); m1 *= (1.f / HID); m2 *= (1.f / HID); m3 *= (1.f / HID);
    float d0 = y0 - m0, d1 = y1 - m1, d2 = y2 - m2, d3 = y3 - m3;
    float v0 = d0 * d0, v1 = d1 * d1, v2 = d2 * d2, v3 = d3 * d3;
#pragma unroll
    for (int s = 32; s > 0; s >>= 1) {
        v0 += __shfl_xor(v0, s, 64);
        v1 += __shfl_xor(v1, s, 64);
        v2 += __shfl_xor(v2, s, 64);
        v3 += __shfl_xor(v3, s, 64);
    }
    v0 *= (1.f / HID); v1 *= (1.f / HID); v2 *= (1.f / HID); v3 *= (1.f / HID);
    h[(size_t)(n0 + nb) * HID + c]     = fmaxf(d0 * rsqrtf(v0 + 1e-5f) * g + bb, 0.f);
    h[(size_t)(n0 + nb + 1) * HID + c] = fmaxf(d1 * rsqrtf(v1 + 1e-5f) * g + bb, 0.f);
    h[(size_t)(n0 + nb + 2) * HID + c] = fmaxf(d2 * rsqrtf(v2 + 1e-5f) * g + bb, 0.f);
    h[(size_t)(n0 + nb + 3) * HID + c] = fmaxf(d3 * rsqrtf(v3 + 1e-5f) * g + bb, 0.f);
}

// ---------------- pool stage 1: segment partial sums + atomics (batch sorted) ----------------
__global__ void gt_pool_sum(const float* __restrict__ h, const int* __restrict__ batch,
                            float* __restrict__ psum) {
    int t = threadIdx.x;
    int c = t & 63, slot = t >> 6;
    int n0 = blockIdx.x * 256;
    float acc = 0.f;
    int curg = -1;
    for (int i = slot; i < 256; i += 4) {
        int n = n0 + i;
        if (n >= NN) break;
        int g = clampi(batch[n], 0, NGRAPHS - 1);
        float val = h[(size_t)n * HID + c];
        if (g != curg) {
            if (curg >= 0) atomicAdd(&psum[curg * HID + c], acc);
            curg = g;
            acc = 0.f;
        }
        acc += val;
    }
    if (curg >= 0) atomicAdd(&psum[curg * HID + c], acc);
}

// ---------------- pool stage 2: divide by true count + classifier ----------------
__global__ void gt_classify(const float* __restrict__ psum, const int* __restrict__ batch,
                            const float* __restrict__ W, const float* __restrict__ b,
                            float* __restrict__ out) {
    int g = blockIdx.x;
    int c = threadIdx.x;
    __shared__ float pooled[HID];
    __shared__ float lg[4];
    __shared__ int bounds[2];
    if (c < 2) {
        int target = g + c;
        int lo = 0, hi = NN;
        while (lo < hi) {
            int mid = (lo + hi) >> 1;
            if (batch[mid] < target) lo = mid + 1; else hi = mid;
        }
        bounds[c] = lo;
    }
    __syncthreads();
    float divf = fmaxf((float)(bounds[1] - bounds[0]), 1.f);
    pooled[c] = psum[g * HID + c] / divf;
    __syncthreads();
    if (c < NCLASSES) {
        float acc = 0.f;
        for (int j = 0; j < HID; ++j) acc += pooled[j] * W[j * NCLASSES + c];
        lg[c] = acc + b[c];
    }
    __syncthreads();
    if (c == 0) {
        float m = fmaxf(lg[0], fmaxf(lg[1], lg[2]));
        float ssum = 0.f;
        for (int cc = 0; cc < NCLASSES; ++cc) ssum += __expf(lg[cc] - m);
        float lse = logf(ssum);
        for (int cc = 0; cc < NCLASSES; ++cc) out[g * NCLASSES + cc] = lg[cc] - m - lse;
    }
}

extern "C" void kernel_launch(void* const* d_in, const int* in_sizes, int n_in,
                              void* d_out, int out_size, void* d_ws, size_t ws_size,
                              hipStream_t stream) {
    float* out = (float*)d_out;

    static const int EXPECT[23] = {2560000, 2048000, 8192, 64, 512, 64, 4096, 64,
                                   49152, 768, 49152, 768, 49152, 768, 49152,
                                   12288, 192, 192, 192, 192, 3, 512000, 20000};
    int bad = -1;
    if (n_in != 23) bad = 99;
    else {
        for (int i = 0; i < 23; ++i) {
            if (in_sizes[i] != EXPECT[i]) { bad = i; break; }
        }
    }
    if (bad >= 0) {
        float val = (bad == 99) ? 4000.f : (5000.f + 10.f * bad);
        gt_write_const<<<1, 256, 0, stream>>>(out, out_size, val);
        return;
    }

    const float* x        = (const float*)d_in[0];
    const float* edge_attr= (const float*)d_in[1];
    const float* node_W   = (const float*)d_in[2];
    const float* node_b   = (const float*)d_in[3];
    const float* e1_W     = (const float*)d_in[4];
    const float* e1_b     = (const float*)d_in[5];
    const float* e2_W     = (const float*)d_in[6];
    const float* e2_b     = (const float*)d_in[7];
    const float* Wq       = (const float*)d_in[8];
    const float* bq       = (const float*)d_in[9];
    const float* Wk       = (const float*)d_in[10];
    const float* bk       = (const float*)d_in[11];
    const float* Wv       = (const float*)d_in[12];
    const float* bv       = (const float*)d_in[13];
    const float* We       = (const float*)d_in[14];
    const float* Wskip    = (const float*)d_in[15];
    const float* bskip    = (const float*)d_in[16];
    const float* lng      = (const float*)d_in[17];
    const float* lnb      = (const float*)d_in[18];
    const float* cls_W    = (const float*)d_in[19];
    const float* cls_b    = (const float*)d_in[20];
    const int*   ei       = (const int*)d_in[21];
    const int*   batch    = (const int*)d_in[22];

    char* w = (char*)d_ws;
    auto alloc = [&](size_t bytes) -> char* {
        char* p = w;
        w += (bytes + 255) & ~(size_t)255;
        return p;
    };
    float* h     = (float*)alloc((size_t)NN * HID * 4);
    bf16*  ef    = (bf16*)alloc((size_t)NE * HID * 2);
    float* q     = (float*)alloc((size_t)NN * HC * 4);
    bf16*  kv    = (bf16*)alloc((size_t)NN * 512 * 2);
    bf16*  qe    = (bf16*)alloc((size_t)NN * HC * 2);
    float* vm    = (float*)alloc((size_t)NN * HID * 4);
    float* Wqe   = (float*)alloc((size_t)NLAYERS * HID * HC * 4);
    float* bias4 = (float*)alloc((size_t)NLAYERS * 1024 * 4);
    bf16*  Bp    = (bf16*)alloc((size_t)NLAYERS * 8192 * 8 * 2);
    bf16*  B2p   = (bf16*)alloc((size_t)512 * 8 * 2);
    float* Wc    = (float*)alloc((size_t)NLAYERS * 320 * 64 * 4);
    float* psum  = (float*)alloc((size_t)NGRAPHS * HID * 4);
    int*   cnt   = (int*)alloc((size_t)NN * 4);
    int*   rp    = (int*)alloc((size_t)(NN + 1) * 4);
    int*   cur   = (int*)alloc((size_t)NN * 4);
    int*   csr   = (int*)alloc((size_t)NE * 4);

    gt_node_proj<<<(NN + 3) / 4, 256, 0, stream>>>(x, node_W, node_b, h);
    gt_prep_wqe<<<NLAYERS * 65, 256, 0, stream>>>(Wq, bq, bk, bv, We, Wqe, bias4);
    gt_pack_qkv<<<(NLAYERS * 8192 + 255) / 256, 256, 0, stream>>>(Wq, Wk, Wv, Wqe, Bp);
    gt_pack_w2<<<2, 256, 0, stream>>>(e2_W, B2p);
    gt_edge_mlp<<<NE / EB, 256, 0, stream>>>(edge_attr, e1_W, e1_b, B2p, e2_b, ef);
    gt_prep_wcomb<<<(NLAYERS * 320 * 64 + 255) / 256, 256, 0, stream>>>(We, Wskip, Wc);
    gt_zero_i32<<<(NN + 255) / 256, 256, 0, stream>>>(cnt, NN);
    gt_count_dst<<<(NE + 255) / 256, 256, 0, stream>>>(ei, cnt);
    gt_scan_csr<<<1, 256, 0, stream>>>(cnt, rp, cur);
    gt_fill_csr<<<(NE + 255) / 256, 256, 0, stream>>>(ei, cur, csr);

    for (int l = 0; l < NLAYERS; ++l) {
        const bf16* Bp_l  = Bp + (size_t)l * 8192 * 8;
        const float* b4_l = bias4 + (size_t)l * 1024;
        const float* Wc_l = Wc + (size_t)l * 320 * 64;
        const float* bs_l = bskip + (size_t)l * HID;
        const float* lg_l = lng + (size_t)l * HID;
        const float* lb_l = lnb + (size_t)l * HID;

        gt_qkv_mfma<<<NN / 16, 256, 0, stream>>>(h, Bp_l, b4_l, q, kv, qe);
        gt_attn_core<<<(NN + 3) / 4, 256, 0, stream>>>(q, qe, kv, ef, rp, csr, ei, vm);
        gt_epilogue<<<NN / EPB, 256, 0, stream>>>(q, vm, Wc_l, bs_l, lg_l, lb_l, h);
    }

    gt_zero_i32<<<(NGRAPHS * HID + 255) / 256, 256, 0, stream>>>((int*)psum, NGRAPHS * HID);
    gt_pool_sum<<<(NN + 255) / 256, 256, 0, stream>>>(h, batch, psum);
    gt_classify<<<NGRAPHS, HID, 0, stream>>>(psum, batch, cls_W, cls_b, out);
}